// Round 3
// baseline (1598.083 us; speedup 1.0000x reference)
//
#include <hip/hip_runtime.h>
#include <hip/hip_bf16.h>
#include <cstdint>

#define B_    8
#define L_    2048
#define C_    1024
#define H_    16
#define D_    64
#define BL_   16384
#define C2_   2048
#define HID_  4096
#define KMAX_ 512

typedef unsigned short u16;
typedef unsigned int   u32;
typedef __attribute__((ext_vector_type(8))) short short8;   // 8 bf16 (4 VGPRs)
typedef __attribute__((ext_vector_type(4))) float f32x4;

__device__ __forceinline__ u16 f2bf(float f){
  u32 u = __float_as_uint(f);
  u += 0x7fffu + ((u >> 16) & 1u);      // RNE; inputs finite
  return (u16)(u >> 16);
}
__device__ __forceinline__ float bf2f(u16 v){
  return __uint_as_float(((u32)v) << 16);
}

// ---------------- zero fill ---------------------------------------------------
__global__ __launch_bounds__(256) void zerofill_kernel(float* __restrict__ p, int n){
  int i = blockIdx.x * 256 + threadIdx.x;
  if (i < n) p[i] = 0.f;
}

// ---------------- rope table: theta = 10000^(-j/512) --------------------------
__global__ void rope_table_kernel(float* __restrict__ cosS, float* __restrict__ sinS){
  int t = threadIdx.x;
  if (t < KMAX_){
    float th = powf(10000.f, -(float)t / (float)KMAX_);
    cosS[t] = cosf(th);
    sinS[t] = sinf(th);
  }
}

// ---------------- f32 (R,Ccol) -> bf16 (Ccol,R) transpose ---------------------
__global__ __launch_bounds__(256) void transpose_bf16_kernel(
    const float* __restrict__ in, u16* __restrict__ out, int R, int Ccol)
{
  __shared__ float tile[32][33];
  int tx = threadIdx.x & 31, ty = threadIdx.x >> 5;   // 32 x 8
  int c = blockIdx.x * 32 + tx;
  #pragma unroll
  for (int i = 0; i < 4; ++i){
    int r = blockIdx.y * 32 + ty + i * 8;
    tile[ty + i * 8][tx] = in[(size_t)r * Ccol + c];
  }
  __syncthreads();
  int rr = blockIdx.y * 32 + tx;
  #pragma unroll
  for (int i = 0; i < 4; ++i){
    int cc = blockIdx.x * 32 + ty + i * 8;
    out[(size_t)cc * R + rr] = f2bf(tile[tx][ty + i * 8]);
  }
}

// ---------------- depthwise conv3 (+x residual) + LayerNorm -------------------
template<typename T>
__global__ __launch_bounds__(256) void cpe_ln_kernel(
    const T* __restrict__ xin, const float* __restrict__ cw, const float* __restrict__ cb,
    const float* __restrict__ g,   const float* __restrict__ beta,
    u16* __restrict__ xout, u16* __restrict__ xnout)
{
  int bl = blockIdx.x;
  int l  = bl & (L_ - 1);
  const T* xr = xin + (size_t)bl * C_;
  int t = threadIdx.x;
  float vals[4];
  float s = 0.f, ss = 0.f;
  #pragma unroll
  for (int i = 0; i < 4; ++i){
    int c = t + i * 256;
    float xm = (l > 0)      ? (float)xr[c - C_] : 0.f;
    float x0 = (float)xr[c];
    float xp = (l < L_ - 1) ? (float)xr[c + C_] : 0.f;
    float v = x0 + xm * cw[c*3] + x0 * cw[c*3+1] + xp * cw[c*3+2] + cb[c];
    vals[i] = v; s += v; ss += v * v;
  }
  int lane = t & 63, w = t >> 6;
  #pragma unroll
  for (int o = 32; o > 0; o >>= 1){ s += __shfl_down(s, o); ss += __shfl_down(ss, o); }
  __shared__ float red[8];
  __shared__ float sh[2];
  if (lane == 0){ red[w] = s; red[4 + w] = ss; }
  __syncthreads();
  if (t == 0){
    float S  = red[0] + red[1] + red[2] + red[3];
    float SS = red[4] + red[5] + red[6] + red[7];
    float mu = S * (1.f / C_);
    float var = SS * (1.f / C_) - mu * mu;
    sh[0] = mu; sh[1] = rsqrtf(var + 1e-5f);
  }
  __syncthreads();
  float mu = sh[0], inv = sh[1];
  #pragma unroll
  for (int i = 0; i < 4; ++i){
    int c = t + i * 256;
    float xn = (vals[i] - mu) * inv * g[c] + beta[c];
    xout[(size_t)bl * C_ + c]  = f2bf(vals[i]);
    xnout[(size_t)bl * C_ + c] = f2bf(xn);
  }
}
template<> __global__ __launch_bounds__(256) void cpe_ln_kernel<u16>(
    const u16* __restrict__ xin, const float* __restrict__ cw, const float* __restrict__ cb,
    const float* __restrict__ g,   const float* __restrict__ beta,
    u16* __restrict__ xout, u16* __restrict__ xnout)
{
  int bl = blockIdx.x;
  int l  = bl & (L_ - 1);
  const u16* xr = xin + (size_t)bl * C_;
  int t = threadIdx.x;
  float vals[4];
  float s = 0.f, ss = 0.f;
  #pragma unroll
  for (int i = 0; i < 4; ++i){
    int c = t + i * 256;
    float xm = (l > 0)      ? bf2f(xr[c - C_]) : 0.f;
    float x0 = bf2f(xr[c]);
    float xp = (l < L_ - 1) ? bf2f(xr[c + C_]) : 0.f;
    float v = x0 + xm * cw[c*3] + x0 * cw[c*3+1] + xp * cw[c*3+2] + cb[c];
    vals[i] = v; s += v; ss += v * v;
  }
  int lane = t & 63, w = t >> 6;
  #pragma unroll
  for (int o = 32; o > 0; o >>= 1){ s += __shfl_down(s, o); ss += __shfl_down(ss, o); }
  __shared__ float red[8];
  __shared__ float sh[2];
  if (lane == 0){ red[w] = s; red[4 + w] = ss; }
  __syncthreads();
  if (t == 0){
    float S  = red[0] + red[1] + red[2] + red[3];
    float SS = red[4] + red[5] + red[6] + red[7];
    float mu = S * (1.f / C_);
    float var = SS * (1.f / C_) - mu * mu;
    sh[0] = mu; sh[1] = rsqrtf(var + 1e-5f);
  }
  __syncthreads();
  float mu = sh[0], inv = sh[1];
  #pragma unroll
  for (int i = 0; i < 4; ++i){
    int c = t + i * 256;
    float xn = (vals[i] - mu) * inv * g[c] + beta[c];
    xout[(size_t)bl * C_ + c]  = f2bf(vals[i]);
    xnout[(size_t)bl * C_ + c] = f2bf(xn);
  }
}

// ---------------- depthwise conv3 + bias + silu (bf16 in -> bf16 out) --------
__global__ __launch_bounds__(256) void dwconv_silu_kernel(
    const u16* __restrict__ xin, const float* __restrict__ w, const float* __restrict__ bias,
    u16* __restrict__ xb)
{
  int bl = blockIdx.x;
  int l  = bl & (L_ - 1);
  const u16* xr = xin + (size_t)bl * C_;
  int t = threadIdx.x;
  #pragma unroll
  for (int i = 0; i < 4; ++i){
    int c = t + i * 256;
    float xm = (l > 0)      ? bf2f(xr[c - C_]) : 0.f;
    float x0 = bf2f(xr[c]);
    float xp = (l < L_ - 1) ? bf2f(xr[c + C_]) : 0.f;
    float v = xm * w[c*3] + x0 * w[c*3+1] + xp * w[c*3+2] + bias[c];
    v = v / (1.f + expf(-v));
    xb[(size_t)bl * C_ + c] = f2bf(v);
  }
}

// ---------------- column mean of k-half of qkb -> kmean[b][c] ----------------
__global__ __launch_bounds__(256) void colmean_kernel(
    const u16* __restrict__ qkb, float* __restrict__ kmean)
{
  int chunk = blockIdx.x, b = blockIdx.y;
  int l0 = chunk * 64;
  int t = threadIdx.x;
  #pragma unroll
  for (int i = 0; i < 4; ++i){
    int c = t + i * 256;
    float s = 0.f;
    for (int r = 0; r < 64; ++r)
      s += bf2f(qkb[((size_t)(b * L_ + l0 + r)) * C2_ + C_ + c]);
    atomicAdd(&kmean[b * C_ + c], s * (1.f / (float)L_));
  }
}

// ---------------- z[row*16+h] = 1/(q_h . kmean_h + 1e-6) ---------------------
__global__ __launch_bounds__(256) void z_kernel(
    const u16* __restrict__ qkb, const float* __restrict__ kmean,
    float* __restrict__ zg)
{
  int idx = blockIdx.x * 256 + threadIdx.x;   // row*16 + h
  int row = idx >> 4, h = idx & 15;
  int b = row >> 11;
  const u32* qp = (const u32*)(qkb + (size_t)row * C2_ + h * 64);
  const float2* kp = (const float2*)(kmean + b * C_ + h * 64);
  float dot = 0.f;
  #pragma unroll
  for (int i = 0; i < 32; ++i){
    u32 q2 = qp[i]; float2 k2 = kp[i];
    dot += bf2f((u16)(q2 & 0xffff)) * k2.x + bf2f((u16)(q2 >> 16)) * k2.y;
  }
  zg[idx] = 1.f / (dot + 1e-6f);
}

// ---------------- kv partial: per (b,h,chunk) accumulate k_rope ⊗ v ----------
__global__ __launch_bounds__(256) void kv_partial_kernel(
    const u16* __restrict__ qkb, const u16* __restrict__ xi,
    const float* __restrict__ cosS, const float* __restrict__ sinS,
    float* __restrict__ part)
{
  int bh = blockIdx.x, cy = blockIdx.y;
  int b = bh >> 4, h = bh & 15;
  __shared__ float kl[8][64];
  __shared__ float vl[8][64];
  int t = threadIdx.x;
  int rs = t >> 5, j = t & 31;          // staging role: row, pair
  int d  = t >> 2, e0 = (t & 3) << 4;   // compute role
  float cj = cosS[h * 32 + j], sj = sinS[h * 32 + j];
  float acc[16];
  #pragma unroll
  for (int e = 0; e < 16; ++e) acc[e] = 0.f;
  int l0 = cy * 512;
  for (int it = 0; it < 64; ++it){
    int l = l0 + it * 8 + rs;
    u32 kp = *(const u32*)(qkb + ((size_t)(b * L_ + l)) * C2_ + C_ + h * 64 + 2 * j);
    float k0 = bf2f((u16)(kp & 0xffff)), k1 = bf2f((u16)(kp >> 16));
    kl[rs][2*j]   = k0 * cj - k1 * sj;
    kl[rs][2*j+1] = k0 * sj + k1 * cj;
    u32 vp = *(const u32*)(xi + ((size_t)(b * L_ + l)) * C_ + h * 64 + 2 * j);
    vl[rs][2*j]   = bf2f((u16)(vp & 0xffff));
    vl[rs][2*j+1] = bf2f((u16)(vp >> 16));
    __syncthreads();
    #pragma unroll
    for (int r = 0; r < 8; ++r){
      float kd = kl[r][d];
      #pragma unroll
      for (int e = 0; e < 16; ++e) acc[e] += kd * vl[r][e0 + e];
    }
    __syncthreads();
  }
  float* po = part + ((size_t)(bh * 4 + cy)) * 4096 + d * 64 + e0;
  #pragma unroll
  for (int e = 0; e < 16; ++e) po[e] = acc[e];
}

__global__ __launch_bounds__(256) void kv_reduce_kernel(
    const float* __restrict__ part, float* __restrict__ kv)
{
  int bh = blockIdx.x;
  int t = threadIdx.x;
  #pragma unroll
  for (int i = 0; i < 16; ++i){
    int o = t + i * 256;
    float s = 0.f;
    #pragma unroll
    for (int cy = 0; cy < 4; ++cy)
      s += part[((size_t)(bh * 4 + cy)) * 4096 + o];
    kv[(size_t)bh * 4096 + o] = s * (1.f / (float)L_);
  }
}

// ---------------- fused attention epilogue -----------------------------------
// grid (rc=8, b=8, h=16): each block owns one head x 256 rows; kv staged once.
__global__ __launch_bounds__(256) void attn_kernel(
    const u16* __restrict__ qkb, const u16* __restrict__ xi,
    const float* __restrict__ kv,  const float* __restrict__ zg,
    const float* __restrict__ cosS, const float* __restrict__ sinS,
    const float* __restrict__ lw,  const float* __restrict__ lb,
    const u16* __restrict__ actres, u16* __restrict__ gout)
{
  int rc = blockIdx.x, b = blockIdx.y, h = blockIdx.z;
  __shared__ float kvs[64][64];   // 16 KB: kv head slice, resident whole block
  __shared__ float qr[16][64];    // 4 KB: roped q chunk
  int t = threadIdx.x;
  const float* kvp = kv + ((size_t)(b * H_ + h)) * 4096;
  #pragma unroll
  for (int i = 0; i < 16; ++i) ((float*)kvs)[t + i * 256] = kvp[t + i * 256];
  int e = t & 63, rq = (t >> 6) * 4;
  int c = h * 64 + e;
  float w0 = lw[c*3], w1 = lw[c*3+1], w2 = lw[c*3+2], bb = lb[c];
  int js = t & 31;
  float cj = cosS[h * 32 + js], sj = sinS[h * 32 + js];
  __syncthreads();
  for (int ch = 0; ch < 16; ++ch){
    int n0 = rc * 256 + ch * 16;
    #pragma unroll
    for (int i = 0; i < 2; ++i){         // stage 16 rows x 32 pairs, roped
      int id = t + i * 256;
      int r = id >> 5;                   // j == js (low 5 bits unchanged)
      u32 q2 = *(const u32*)(qkb + ((size_t)(b * L_ + n0 + r)) * C2_ + h * 64 + 2 * js);
      float q0 = bf2f((u16)(q2 & 0xffff)), q1 = bf2f((u16)(q2 >> 16));
      qr[r][2*js]   = q0 * cj - q1 * sj;
      qr[r][2*js+1] = q0 * sj + q1 * cj;
    }
    __syncthreads();
    float a[4] = {0.f, 0.f, 0.f, 0.f};
    #pragma unroll
    for (int d = 0; d < 64; ++d){
      float kvv = kvs[d][e];
      #pragma unroll
      for (int jj = 0; jj < 4; ++jj) a[jj] += qr[rq + jj][d] * kvv;
    }
    #pragma unroll
    for (int jj = 0; jj < 4; ++jj){
      int n = n0 + rq + jj;
      size_t row = (size_t)(b * L_) + n;
      float attnv = a[jj] * zg[(row << 4) + h];
      float vm = (n > 0)      ? bf2f(xi[(row - 1) * C_ + c]) : 0.f;
      float v0 = bf2f(xi[row * C_ + c]);
      float vp = (n < L_ - 1) ? bf2f(xi[(row + 1) * C_ + c]) : 0.f;
      float gval = (attnv + vm * w0 + v0 * w1 + vp * w2 + bb) * bf2f(actres[row * C_ + c]);
      gout[row * C_ + c] = f2bf(gval);
    }
    __syncthreads();
  }
}

// ---------------- bf16 MFMA GEMM, 128x128 tile, BK=64, templated epilogue ----
enum { EP_SILU = 0, EP_NONE = 1, EP_ELU1 = 2, EP_RES_BF = 3, EP_GELU = 4, EP_RES_F32 = 5 };

template<int EP>
__global__ __launch_bounds__(256) void gemm_bf16(
    const u16* __restrict__ A,    // M x K bf16 row-major
    const u16* __restrict__ Bt,   // N x K bf16 row-major (pre-transposed weight)
    const float* __restrict__ bias,
    const u16* __restrict__ res,  // bf16 residual (EP_RES_*)
    float* __restrict__ outF, u16* __restrict__ outB,
    int M, int N, int K)
{
  __shared__ u16 As[128 * 64];
  __shared__ u16 Bs[128 * 64];
  const int t = threadIdx.x;
  const int m0 = blockIdx.x * 128;
  const int n0 = blockIdx.y * 128;
  const int lane = t & 63, w = t >> 6;
  const int wm = (w >> 1) * 64, wn = (w & 1) * 64;
  f32x4 acc[4][4] = {};
  const int ktiles = K >> 6;
  for (int kt = 0; kt < ktiles; ++kt){
    const u16* Ab = A  + (size_t)m0 * K + kt * 64;
    const u16* Bb = Bt + (size_t)n0 * K + kt * 64;
    #pragma unroll
    for (int i = 0; i < 4; ++i){
      int idx = t + i * 256;
      int row = idx >> 3, k8 = idx & 7;
      int so = row * 64 + ((k8 * 8) ^ ((row & 7) << 3));   // XOR-swizzle (bank fix)
      *(uint4*)(&As[so]) = *(const uint4*)(Ab + (size_t)row * K + k8 * 8);
      *(uint4*)(&Bs[so]) = *(const uint4*)(Bb + (size_t)row * K + k8 * 8);
    }
    __syncthreads();
    #pragma unroll
    for (int ks = 0; ks < 2; ++ks){
      short8 af[4], bfr[4];
      int kk = ks * 32 + ((lane >> 4) << 3);
      #pragma unroll
      for (int mi = 0; mi < 4; ++mi){
        int row = wm + mi * 16 + (lane & 15);
        af[mi] = *(const short8*)(&As[row * 64 + (kk ^ ((row & 7) << 3))]);
      }
      #pragma unroll
      for (int ni = 0; ni < 4; ++ni){
        int row = wn + ni * 16 + (lane & 15);
        bfr[ni] = *(const short8*)(&Bs[row * 64 + (kk ^ ((row & 7) << 3))]);
      }
      #pragma unroll
      for (int mi = 0; mi < 4; ++mi)
        #pragma unroll
        for (int ni = 0; ni < 4; ++ni)
          acc[mi][ni] = __builtin_amdgcn_mfma_f32_16x16x32_bf16(af[mi], bfr[ni], acc[mi][ni], 0, 0, 0);
    }
    __syncthreads();
  }
  // epilogue: D row = (lane>>4)*4 + reg, col = lane&15
  #pragma unroll
  for (int mi = 0; mi < 4; ++mi){
    #pragma unroll
    for (int ni = 0; ni < 4; ++ni){
      int gmb = m0 + wm + mi * 16 + ((lane >> 4) << 2);
      int gn  = n0 + wn + ni * 16 + (lane & 15);
      float bv = bias[gn];
      #pragma unroll
      for (int r = 0; r < 4; ++r){
        int gm = gmb + r;
        float v = acc[mi][ni][r] + bv;
        size_t o = (size_t)gm * N + gn;
        if (EP == EP_SILU)      outB[o] = f2bf(v / (1.f + expf(-v)));
        else if (EP == EP_NONE) outB[o] = f2bf(v);
        else if (EP == EP_ELU1) outB[o] = f2bf((v > 0.f) ? (v + 1.f) : expf(v));
        else if (EP == EP_RES_BF) outB[o] = f2bf(v + bf2f(res[o]));
        else if (EP == EP_GELU) outB[o] = f2bf(0.5f * v * (1.f + erff(v * 0.70710678118f)));
        else if (EP == EP_RES_F32) outF[o] = v + bf2f(res[o]);
      }
    }
  }
}

// ------------------------------- launcher ------------------------------------
extern "C" void kernel_launch(void* const* d_in, const int* in_sizes, int n_in,
                              void* d_out, int out_size, void* d_ws, size_t ws_size,
                              hipStream_t stream)
{
  const float* x       = (const float*)d_in[0];
  const float* cpe1_w  = (const float*)d_in[1];
  const float* cpe1_b  = (const float*)d_in[2];
  const float* norm1_g = (const float*)d_in[3];
  const float* norm1_b = (const float*)d_in[4];
  const float* in_w    = (const float*)d_in[5];
  const float* in_b    = (const float*)d_in[6];
  const float* actp_w  = (const float*)d_in[7];
  const float* actp_b  = (const float*)d_in[8];
  const float* dwc_w   = (const float*)d_in[9];
  const float* dwc_b   = (const float*)d_in[10];
  const float* qk_w    = (const float*)d_in[11];
  const float* qk_b    = (const float*)d_in[12];
  const float* lepe_w  = (const float*)d_in[13];
  const float* lepe_b  = (const float*)d_in[14];
  const float* out_w   = (const float*)d_in[15];
  const float* out_b   = (const float*)d_in[16];
  const float* cpe2_w  = (const float*)d_in[17];
  const float* cpe2_b  = (const float*)d_in[18];
  const float* norm2_g = (const float*)d_in[19];
  const float* norm2_b = (const float*)d_in[20];
  const float* fc1_w   = (const float*)d_in[21];
  const float* fc1_b   = (const float*)d_in[22];
  const float* fc2_w   = (const float*)d_in[23];
  const float* fc2_b   = (const float*)d_in[24];
  float* out = (float*)d_out;

  char* ws = (char*)d_ws;
  size_t off = 0;
  auto alloc = [&](size_t bytes) -> char* {
    char* p = ws + off;
    off = (off + bytes + 255) & ~(size_t)255;
    return p;
  };
  float* cosS   = (float*)alloc(KMAX_ * 4);
  float* sinS   = (float*)alloc(KMAX_ * 4);
  u16* wTactp   = (u16*)alloc((size_t)C_ * C_ * 2);
  u16* wTin     = (u16*)alloc((size_t)C_ * C_ * 2);
  u16* wTqk     = (u16*)alloc((size_t)C2_ * C_ * 2);
  u16* wTout    = (u16*)alloc((size_t)C_ * C_ * 2);
  u16* wTfc1    = (u16*)alloc((size_t)HID_ * C_ * 2);
  u16* wTfc2    = (u16*)alloc((size_t)C_ * HID_ * 2);
  float* kmean  = (float*)alloc((size_t)B_ * C_ * 4);
  float* kv     = (float*)alloc((size_t)128 * 4096 * 4);
  float* kvpart = (float*)alloc((size_t)512 * 4096 * 4);
  float* zbuf   = (float*)alloc((size_t)BL_ * H_ * 4);
  u16* x1       = (u16*)alloc((size_t)BL_ * C_ * 2);        // shortcut (bf16)
  u16* bufX     = (u16*)alloc((size_t)BL_ * C_ * 2);        // xn / g / xn2
  u16* bufY     = (u16*)alloc((size_t)BL_ * C_ * 2);        // act_res -> x3
  u16* bufW     = (u16*)alloc((size_t)BL_ * C_ * 2);        // xi -> MLP hidden chunk
  u16* bufQ     = (u16*)alloc((size_t)BL_ * C2_ * 2);       // xi0(lo) -> qkb -> x2(lo)
  size_t needed = off;
  if (ws_size < needed) return;   // diagnostic: clean failure instead of OOB fault

  u16* xi0 = bufQ;        // 32MB (lower half)
  u16* qkb = bufQ;        // full 64MB
  u16* x2  = bufQ;        // 32MB (lower half), after qkb dead
  u16* xi  = bufW;
  u16* hb  = bufW;        // MLP hidden chunk (after xi dead)
  u16* actres = bufY;
  u16* x3  = bufY;

  rope_table_kernel<<<1, 512, 0, stream>>>(cosS, sinS);
  transpose_bf16_kernel<<<dim3(C_/32,  C_/32 ), 256, 0, stream>>>(actp_w, wTactp, C_,  C_);
  transpose_bf16_kernel<<<dim3(C_/32,  C_/32 ), 256, 0, stream>>>(in_w,   wTin,   C_,  C_);
  transpose_bf16_kernel<<<dim3(C2_/32, C_/32 ), 256, 0, stream>>>(qk_w,   wTqk,   C_,  C2_);
  transpose_bf16_kernel<<<dim3(C_/32,  C_/32 ), 256, 0, stream>>>(out_w,  wTout,  C_,  C_);
  transpose_bf16_kernel<<<dim3(HID_/32,C_/32 ), 256, 0, stream>>>(fc1_w,  wTfc1,  C_,  HID_);
  transpose_bf16_kernel<<<dim3(C_/32,  HID_/32), 256, 0, stream>>>(fc2_w,  wTfc2,  HID_, C_);
  zerofill_kernel<<<(B_*C_ + 255)/256, 256, 0, stream>>>(kmean, B_*C_);

  // x = x + cpe1(x); shortcut=x1; xn = LN(x)
  cpe_ln_kernel<float><<<BL_, 256, 0, stream>>>(x, cpe1_w, cpe1_b, norm1_g, norm1_b, x1, bufX);
  // act_res = silu(xn @ actp_w + b)
  gemm_bf16<EP_SILU><<<dim3(BL_/128, C_/128), 256, 0, stream>>>(
      bufX, wTactp, actp_b, nullptr, nullptr, actres, BL_, C_, C_);
  // xi0 = xn @ in_w + b
  gemm_bf16<EP_NONE><<<dim3(BL_/128, C_/128), 256, 0, stream>>>(
      bufX, wTin, in_b, nullptr, nullptr, xi0, BL_, C_, C_);
  // xi = silu(dwc(xi0))
  dwconv_silu_kernel<<<BL_, 256, 0, stream>>>(xi0, dwc_w, dwc_b, xi);
  // qkb = elu(xi @ qk_w + b) + 1
  gemm_bf16<EP_ELU1><<<dim3(BL_/128, C2_/128), 256, 0, stream>>>(
      xi, wTqk, qk_b, nullptr, nullptr, qkb, BL_, C2_, C_);
  // kmean, z, kv
  colmean_kernel<<<dim3(32, B_), 256, 0, stream>>>(qkb, kmean);
  z_kernel<<<BL_*H_/256, 256, 0, stream>>>(qkb, kmean, zbuf);
  kv_partial_kernel<<<dim3(128, 4), 256, 0, stream>>>(qkb, xi, cosS, sinS, kvpart);
  kv_reduce_kernel<<<128, 256, 0, stream>>>(kvpart, kv);
  // attn + lepe + gating -> g (bf16, bufX overwrites xn)
  attn_kernel<<<dim3(8, B_, H_), 256, 0, stream>>>(
      qkb, xi, kv, zbuf, cosS, sinS, lepe_w, lepe_b, actres, bufX);
  // x2 = x1 + g @ out_w + b   (bf16, into bufQ lower half; qkb dead)
  gemm_bf16<EP_RES_BF><<<dim3(BL_/128, C_/128), 256, 0, stream>>>(
      bufX, wTout, out_b, x1, nullptr, x2, BL_, C_, C_);
  // x3 = x2 + cpe2(x2); xn2 = LN2(x3)
  cpe_ln_kernel<u16><<<BL_, 256, 0, stream>>>(x2, cpe2_w, cpe2_b, norm2_g, norm2_b, x3, bufX);
  // MLP in 4 row-chunks of 4096 (hidden chunk lives in bufW; xi dead)
  for (int m = 0; m < 4; ++m){
    size_t ro = (size_t)m * 4096;
    gemm_bf16<EP_GELU><<<dim3(32, HID_/128), 256, 0, stream>>>(
        bufX + ro * C_, wTfc1, fc1_b, nullptr, nullptr, hb, 4096, HID_, C_);
    gemm_bf16<EP_RES_F32><<<dim3(32, C_/128), 256, 0, stream>>>(
        hb, wTfc2, fc2_b, x3 + ro * C_, out + ro * C_, nullptr, 4096, C_, HID_);
  }
}

// Round 4
// 1475.539 us; speedup vs baseline: 1.0831x; 1.0831x over previous
//
#include <hip/hip_runtime.h>
#include <hip/hip_bf16.h>
#include <cstdint>

#define B_    8
#define L_    2048
#define C_    1024
#define H_    16
#define D_    64
#define BL_   16384
#define C2_   2048
#define HID_  4096
#define KMAX_ 512

typedef unsigned short u16;
typedef unsigned int   u32;
typedef __attribute__((ext_vector_type(8))) short short8;   // 8 bf16 (4 VGPRs)
typedef __attribute__((ext_vector_type(4))) float f32x4;

__device__ __forceinline__ u16 f2bf(float f){
  u32 u = __float_as_uint(f);
  u += 0x7fffu + ((u >> 16) & 1u);      // RNE; inputs finite
  return (u16)(u >> 16);
}
__device__ __forceinline__ float bf2f(u16 v){
  return __uint_as_float(((u32)v) << 16);
}

// ---------------- zero fill ---------------------------------------------------
__global__ __launch_bounds__(256) void zerofill_kernel(float* __restrict__ p, int n){
  int i = blockIdx.x * 256 + threadIdx.x;
  if (i < n) p[i] = 0.f;
}

// ---------------- rope table: theta = 10000^(-j/512) --------------------------
__global__ void rope_table_kernel(float* __restrict__ cosS, float* __restrict__ sinS){
  int t = threadIdx.x;
  if (t < KMAX_){
    float th = powf(10000.f, -(float)t / (float)KMAX_);
    cosS[t] = cosf(th);
    sinS[t] = sinf(th);
  }
}

// ---------------- f32 (R,Ccol) -> bf16 (Ccol,R) transpose ---------------------
__global__ __launch_bounds__(256) void transpose_bf16_kernel(
    const float* __restrict__ in, u16* __restrict__ out, int R, int Ccol)
{
  __shared__ float tile[32][33];
  int tx = threadIdx.x & 31, ty = threadIdx.x >> 5;   // 32 x 8
  int c = blockIdx.x * 32 + tx;
  #pragma unroll
  for (int i = 0; i < 4; ++i){
    int r = blockIdx.y * 32 + ty + i * 8;
    tile[ty + i * 8][tx] = in[(size_t)r * Ccol + c];
  }
  __syncthreads();
  int rr = blockIdx.y * 32 + tx;
  #pragma unroll
  for (int i = 0; i < 4; ++i){
    int cc = blockIdx.x * 32 + ty + i * 8;
    out[(size_t)cc * R + rr] = f2bf(tile[tx][ty + i * 8]);
  }
}

// ---------------- depthwise conv3 (+x residual) + LayerNorm -------------------
template<typename T>
__global__ __launch_bounds__(256) void cpe_ln_kernel(
    const T* __restrict__ xin, const float* __restrict__ cw, const float* __restrict__ cb,
    const float* __restrict__ g,   const float* __restrict__ beta,
    u16* __restrict__ xout, u16* __restrict__ xnout)
{
  int bl = blockIdx.x;
  int l  = bl & (L_ - 1);
  const T* xr = xin + (size_t)bl * C_;
  int t = threadIdx.x;
  float vals[4];
  float s = 0.f, ss = 0.f;
  #pragma unroll
  for (int i = 0; i < 4; ++i){
    int c = t + i * 256;
    float xm = (l > 0)      ? (float)xr[c - C_] : 0.f;
    float x0 = (float)xr[c];
    float xp = (l < L_ - 1) ? (float)xr[c + C_] : 0.f;
    float v = x0 + xm * cw[c*3] + x0 * cw[c*3+1] + xp * cw[c*3+2] + cb[c];
    vals[i] = v; s += v; ss += v * v;
  }
  int lane = t & 63, w = t >> 6;
  #pragma unroll
  for (int o = 32; o > 0; o >>= 1){ s += __shfl_down(s, o); ss += __shfl_down(ss, o); }
  __shared__ float red[8];
  __shared__ float sh[2];
  if (lane == 0){ red[w] = s; red[4 + w] = ss; }
  __syncthreads();
  if (t == 0){
    float S  = red[0] + red[1] + red[2] + red[3];
    float SS = red[4] + red[5] + red[6] + red[7];
    float mu = S * (1.f / C_);
    float var = SS * (1.f / C_) - mu * mu;
    sh[0] = mu; sh[1] = rsqrtf(var + 1e-5f);
  }
  __syncthreads();
  float mu = sh[0], inv = sh[1];
  #pragma unroll
  for (int i = 0; i < 4; ++i){
    int c = t + i * 256;
    float xn = (vals[i] - mu) * inv * g[c] + beta[c];
    xout[(size_t)bl * C_ + c]  = f2bf(vals[i]);
    xnout[(size_t)bl * C_ + c] = f2bf(xn);
  }
}
template<> __global__ __launch_bounds__(256) void cpe_ln_kernel<u16>(
    const u16* __restrict__ xin, const float* __restrict__ cw, const float* __restrict__ cb,
    const float* __restrict__ g,   const float* __restrict__ beta,
    u16* __restrict__ xout, u16* __restrict__ xnout)
{
  int bl = blockIdx.x;
  int l  = bl & (L_ - 1);
  const u16* xr = xin + (size_t)bl * C_;
  int t = threadIdx.x;
  float vals[4];
  float s = 0.f, ss = 0.f;
  #pragma unroll
  for (int i = 0; i < 4; ++i){
    int c = t + i * 256;
    float xm = (l > 0)      ? bf2f(xr[c - C_]) : 0.f;
    float x0 = bf2f(xr[c]);
    float xp = (l < L_ - 1) ? bf2f(xr[c + C_]) : 0.f;
    float v = x0 + xm * cw[c*3] + x0 * cw[c*3+1] + xp * cw[c*3+2] + cb[c];
    vals[i] = v; s += v; ss += v * v;
  }
  int lane = t & 63, w = t >> 6;
  #pragma unroll
  for (int o = 32; o > 0; o >>= 1){ s += __shfl_down(s, o); ss += __shfl_down(ss, o); }
  __shared__ float red[8];
  __shared__ float sh[2];
  if (lane == 0){ red[w] = s; red[4 + w] = ss; }
  __syncthreads();
  if (t == 0){
    float S  = red[0] + red[1] + red[2] + red[3];
    float SS = red[4] + red[5] + red[6] + red[7];
    float mu = S * (1.f / C_);
    float var = SS * (1.f / C_) - mu * mu;
    sh[0] = mu; sh[1] = rsqrtf(var + 1e-5f);
  }
  __syncthreads();
  float mu = sh[0], inv = sh[1];
  #pragma unroll
  for (int i = 0; i < 4; ++i){
    int c = t + i * 256;
    float xn = (vals[i] - mu) * inv * g[c] + beta[c];
    xout[(size_t)bl * C_ + c]  = f2bf(vals[i]);
    xnout[(size_t)bl * C_ + c] = f2bf(xn);
  }
}

// ---------------- depthwise conv3 + bias + silu (bf16 in -> bf16 out) --------
__global__ __launch_bounds__(256) void dwconv_silu_kernel(
    const u16* __restrict__ xin, const float* __restrict__ w, const float* __restrict__ bias,
    u16* __restrict__ xb)
{
  int bl = blockIdx.x;
  int l  = bl & (L_ - 1);
  const u16* xr = xin + (size_t)bl * C_;
  int t = threadIdx.x;
  #pragma unroll
  for (int i = 0; i < 4; ++i){
    int c = t + i * 256;
    float xm = (l > 0)      ? bf2f(xr[c - C_]) : 0.f;
    float x0 = bf2f(xr[c]);
    float xp = (l < L_ - 1) ? bf2f(xr[c + C_]) : 0.f;
    float v = xm * w[c*3] + x0 * w[c*3+1] + xp * w[c*3+2] + bias[c];
    v = v / (1.f + expf(-v));
    xb[(size_t)bl * C_ + c] = f2bf(v);
  }
}

// ---------------- column mean of k-half of qkb -> kmean[b][c] ----------------
__global__ __launch_bounds__(256) void colmean_kernel(
    const u16* __restrict__ qkb, float* __restrict__ kmean)
{
  int chunk = blockIdx.x, b = blockIdx.y;
  int l0 = chunk * 64;
  int t = threadIdx.x;
  #pragma unroll
  for (int i = 0; i < 4; ++i){
    int c = t + i * 256;
    float s = 0.f;
    for (int r = 0; r < 64; ++r)
      s += bf2f(qkb[((size_t)(b * L_ + l0 + r)) * C2_ + C_ + c]);
    atomicAdd(&kmean[b * C_ + c], s * (1.f / (float)L_));
  }
}

// ---------------- z[row*16+h] = 1/(q_h . kmean_h + 1e-6) ---------------------
__global__ __launch_bounds__(256) void z_kernel(
    const u16* __restrict__ qkb, const float* __restrict__ kmean,
    float* __restrict__ zg)
{
  int idx = blockIdx.x * 256 + threadIdx.x;   // row*16 + h
  int row = idx >> 4, h = idx & 15;
  int b = row >> 11;
  const u32* qp = (const u32*)(qkb + (size_t)row * C2_ + h * 64);
  const float2* kp = (const float2*)(kmean + b * C_ + h * 64);
  float dot = 0.f;
  #pragma unroll
  for (int i = 0; i < 32; ++i){
    u32 q2 = qp[i]; float2 k2 = kp[i];
    dot += bf2f((u16)(q2 & 0xffff)) * k2.x + bf2f((u16)(q2 >> 16)) * k2.y;
  }
  zg[idx] = 1.f / (dot + 1e-6f);
}

// ---------------- kv partial: per (b,h,chunk) accumulate k_rope ⊗ v ----------
__global__ __launch_bounds__(256) void kv_partial_kernel(
    const u16* __restrict__ qkb, const u16* __restrict__ xi,
    const float* __restrict__ cosS, const float* __restrict__ sinS,
    float* __restrict__ part)
{
  int bh = blockIdx.x, cy = blockIdx.y;
  int b = bh >> 4, h = bh & 15;
  __shared__ float kl[8][64];
  __shared__ float vl[8][64];
  int t = threadIdx.x;
  int rs = t >> 5, j = t & 31;          // staging role: row, pair
  int d  = t >> 2, e0 = (t & 3) << 4;   // compute role
  float cj = cosS[h * 32 + j], sj = sinS[h * 32 + j];
  float acc[16];
  #pragma unroll
  for (int e = 0; e < 16; ++e) acc[e] = 0.f;
  int l0 = cy * 512;
  for (int it = 0; it < 64; ++it){
    int l = l0 + it * 8 + rs;
    u32 kp = *(const u32*)(qkb + ((size_t)(b * L_ + l)) * C2_ + C_ + h * 64 + 2 * j);
    float k0 = bf2f((u16)(kp & 0xffff)), k1 = bf2f((u16)(kp >> 16));
    kl[rs][2*j]   = k0 * cj - k1 * sj;
    kl[rs][2*j+1] = k0 * sj + k1 * cj;
    u32 vp = *(const u32*)(xi + ((size_t)(b * L_ + l)) * C_ + h * 64 + 2 * j);
    vl[rs][2*j]   = bf2f((u16)(vp & 0xffff));
    vl[rs][2*j+1] = bf2f((u16)(vp >> 16));
    __syncthreads();
    #pragma unroll
    for (int r = 0; r < 8; ++r){
      float kd = kl[r][d];
      #pragma unroll
      for (int e = 0; e < 16; ++e) acc[e] += kd * vl[r][e0 + e];
    }
    __syncthreads();
  }
  float* po = part + ((size_t)(bh * 4 + cy)) * 4096 + d * 64 + e0;
  #pragma unroll
  for (int e = 0; e < 16; ++e) po[e] = acc[e];
}

// reduce partials -> kvb bf16 TRANSPOSED [bh][e*64+d] (B-operand layout for MFMA)
__global__ __launch_bounds__(256) void kv_reduce_kernel(
    const float* __restrict__ part, u16* __restrict__ kvb)
{
  int bh = blockIdx.x;
  int t = threadIdx.x;
  #pragma unroll
  for (int i = 0; i < 16; ++i){
    int o = t + i * 256;
    int d = o >> 6, e = o & 63;
    float s = 0.f;
    #pragma unroll
    for (int cy = 0; cy < 4; ++cy)
      s += part[((size_t)(bh * 4 + cy)) * 4096 + o];
    kvb[(size_t)bh * 4096 + e * 64 + d] = f2bf(s * (1.f / (float)L_));
  }
}

// ---------------- fused attention epilogue (MFMA) ----------------------------
// grid (rc=16, b=8, h=16): block owns one head x 128 rows (2 chunks of 64).
// kv held in registers as B-frags; q roped into swizzled LDS; 8 MFMA / chunk / wave.
__global__ __launch_bounds__(256, 4) void attn_kernel(
    const u16* __restrict__ qkb, const u16* __restrict__ xi,
    const u16* __restrict__ kvb, const float* __restrict__ zg,
    const float* __restrict__ cosS, const float* __restrict__ sinS,
    const float* __restrict__ lw,  const float* __restrict__ lb,
    const u16* __restrict__ actres, u16* __restrict__ gout)
{
  int rc = blockIdx.x, b = blockIdx.y, h = blockIdx.z;
  __shared__ u16 qs[64 * 64];          // 8 KB, 128B rows, XOR-swizzled
  int t = threadIdx.x;
  int lane = t & 63, w = t >> 6;
  int bh = b * H_ + h;
  // B-frags: kvb row = output col e, k = d  (8 x 16B loads, live whole kernel)
  short8 bq[4][2];
  #pragma unroll
  for (int ni = 0; ni < 4; ++ni)
    #pragma unroll
    for (int kf = 0; kf < 2; ++kf)
      bq[ni][kf] = *(const short8*)(kvb + (size_t)bh * 4096 +
                     (ni * 16 + (lane & 15)) * 64 + kf * 32 + (lane >> 4) * 8);
  int js = t & 31;
  float cj = cosS[h * 32 + js], sj = sinS[h * 32 + js];
  // lepe weights per output col (hoisted; col independent of chunk)
  float w0[4], w1[4], w2[4], bb[4];
  #pragma unroll
  for (int ni = 0; ni < 4; ++ni){
    int c = h * 64 + ni * 16 + (lane & 15);
    w0[ni] = lw[c*3]; w1[ni] = lw[c*3+1]; w2[ni] = lw[c*3+2]; bb[ni] = lb[c];
  }
  for (int ch = 0; ch < 2; ++ch){
    int n0 = rc * 128 + ch * 64;
    #pragma unroll
    for (int i = 0; i < 8; ++i){       // stage 64 roped rows as bf16
      int id = t + i * 256;
      int r = id >> 5;                 // pair index == js (low 5 bits)
      u32 q2 = *(const u32*)(qkb + ((size_t)(b * L_ + n0 + r)) * C2_ + h * 64 + 2 * js);
      float q0 = bf2f((u16)(q2 & 0xffff)), q1 = bf2f((u16)(q2 >> 16));
      u32 pk = (u32)f2bf(q0 * cj - q1 * sj) | ((u32)f2bf(q0 * sj + q1 * cj) << 16);
      *(u32*)((char*)qs + r * 128 + ((4 * js) ^ ((r & 7) << 4))) = pk;
    }
    __syncthreads();
    int arow = w * 16 + (lane & 15);
    short8 af0 = *(const short8*)((char*)qs + arow * 128 + ((     (lane >> 4) * 16) ^ ((arow & 7) << 4)));
    short8 af1 = *(const short8*)((char*)qs + arow * 128 + ((64 + (lane >> 4) * 16) ^ ((arow & 7) << 4)));
    f32x4 acc[4] = {};
    #pragma unroll
    for (int ni = 0; ni < 4; ++ni){
      acc[ni] = __builtin_amdgcn_mfma_f32_16x16x32_bf16(af0, bq[ni][0], acc[ni], 0, 0, 0);
      acc[ni] = __builtin_amdgcn_mfma_f32_16x16x32_bf16(af1, bq[ni][1], acc[ni], 0, 0, 0);
    }
    #pragma unroll
    for (int ni = 0; ni < 4; ++ni){
      int c = h * 64 + ni * 16 + (lane & 15);
      #pragma unroll
      for (int r = 0; r < 4; ++r){
        int n = n0 + w * 16 + (lane >> 4) * 4 + r;
        size_t row = (size_t)b * L_ + n;
        float attnv = acc[ni][r] * zg[(row << 4) + h];
        float vm = (n > 0)      ? bf2f(xi[(row - 1) * C_ + c]) : 0.f;
        float v0 = bf2f(xi[row * C_ + c]);
        float vp = (n < L_ - 1) ? bf2f(xi[(row + 1) * C_ + c]) : 0.f;
        float gval = (attnv + vm * w0[ni] + v0 * w1[ni] + vp * w2[ni] + bb[ni]) * bf2f(actres[row * C_ + c]);
        gout[row * C_ + c] = f2bf(gval);
      }
    }
    __syncthreads();
  }
}

// ---------------- bf16 MFMA GEMM, 128x128 tile, BK=64, templated epilogue ----
enum { EP_SILU = 0, EP_NONE = 1, EP_ELU1 = 2, EP_RES_BF = 3, EP_GELU = 4, EP_RES_F32 = 5 };

template<int EP>
__global__ __launch_bounds__(256) void gemm_bf16(
    const u16* __restrict__ A,    // M x K bf16 row-major
    const u16* __restrict__ Bt,   // N x K bf16 row-major (pre-transposed weight)
    const float* __restrict__ bias,
    const u16* __restrict__ res,  // bf16 residual (EP_RES_*)
    float* __restrict__ outF, u16* __restrict__ outB,
    int M, int N, int K)
{
  __shared__ u16 As[128 * 64];
  __shared__ u16 Bs[128 * 64];
  const int t = threadIdx.x;
  const int m0 = blockIdx.x * 128;
  const int n0 = blockIdx.y * 128;
  const int lane = t & 63, w = t >> 6;
  const int wm = (w >> 1) * 64, wn = (w & 1) * 64;
  f32x4 acc[4][4] = {};
  const int ktiles = K >> 6;
  for (int kt = 0; kt < ktiles; ++kt){
    const u16* Ab = A  + (size_t)m0 * K + kt * 64;
    const u16* Bb = Bt + (size_t)n0 * K + kt * 64;
    #pragma unroll
    for (int i = 0; i < 4; ++i){
      int idx = t + i * 256;
      int row = idx >> 3, k8 = idx & 7;
      int so = row * 64 + ((k8 * 8) ^ ((row & 7) << 3));   // XOR-swizzle (bank fix)
      *(uint4*)(&As[so]) = *(const uint4*)(Ab + (size_t)row * K + k8 * 8);
      *(uint4*)(&Bs[so]) = *(const uint4*)(Bb + (size_t)row * K + k8 * 8);
    }
    __syncthreads();
    #pragma unroll
    for (int ks = 0; ks < 2; ++ks){
      short8 af[4], bfr[4];
      int kk = ks * 32 + ((lane >> 4) << 3);
      #pragma unroll
      for (int mi = 0; mi < 4; ++mi){
        int row = wm + mi * 16 + (lane & 15);
        af[mi] = *(const short8*)(&As[row * 64 + (kk ^ ((row & 7) << 3))]);
      }
      #pragma unroll
      for (int ni = 0; ni < 4; ++ni){
        int row = wn + ni * 16 + (lane & 15);
        bfr[ni] = *(const short8*)(&Bs[row * 64 + (kk ^ ((row & 7) << 3))]);
      }
      #pragma unroll
      for (int mi = 0; mi < 4; ++mi)
        #pragma unroll
        for (int ni = 0; ni < 4; ++ni)
          acc[mi][ni] = __builtin_amdgcn_mfma_f32_16x16x32_bf16(af[mi], bfr[ni], acc[mi][ni], 0, 0, 0);
    }
    __syncthreads();
  }
  // epilogue: D row = (lane>>4)*4 + reg, col = lane&15
  #pragma unroll
  for (int mi = 0; mi < 4; ++mi){
    #pragma unroll
    for (int ni = 0; ni < 4; ++ni){
      int gmb = m0 + wm + mi * 16 + ((lane >> 4) << 2);
      int gn  = n0 + wn + ni * 16 + (lane & 15);
      float bv = bias[gn];
      #pragma unroll
      for (int r = 0; r < 4; ++r){
        int gm = gmb + r;
        float v = acc[mi][ni][r] + bv;
        size_t o = (size_t)gm * N + gn;
        if (EP == EP_SILU)      outB[o] = f2bf(v / (1.f + expf(-v)));
        else if (EP == EP_NONE) outB[o] = f2bf(v);
        else if (EP == EP_ELU1) outB[o] = f2bf((v > 0.f) ? (v + 1.f) : expf(v));
        else if (EP == EP_RES_BF) outB[o] = f2bf(v + bf2f(res[o]));
        else if (EP == EP_GELU) outB[o] = f2bf(0.5f * v * (1.f + erff(v * 0.70710678118f)));
        else if (EP == EP_RES_F32) outF[o] = v + bf2f(res[o]);
      }
    }
  }
}

// ------------------------------- launcher ------------------------------------
extern "C" void kernel_launch(void* const* d_in, const int* in_sizes, int n_in,
                              void* d_out, int out_size, void* d_ws, size_t ws_size,
                              hipStream_t stream)
{
  const float* x       = (const float*)d_in[0];
  const float* cpe1_w  = (const float*)d_in[1];
  const float* cpe1_b  = (const float*)d_in[2];
  const float* norm1_g = (const float*)d_in[3];
  const float* norm1_b = (const float*)d_in[4];
  const float* in_w    = (const float*)d_in[5];
  const float* in_b    = (const float*)d_in[6];
  const float* actp_w  = (const float*)d_in[7];
  const float* actp_b  = (const float*)d_in[8];
  const float* dwc_w   = (const float*)d_in[9];
  const float* dwc_b   = (const float*)d_in[10];
  const float* qk_w    = (const float*)d_in[11];
  const float* qk_b    = (const float*)d_in[12];
  const float* lepe_w  = (const float*)d_in[13];
  const float* lepe_b  = (const float*)d_in[14];
  const float* out_w   = (const float*)d_in[15];
  const float* out_b   = (const float*)d_in[16];
  const float* cpe2_w  = (const float*)d_in[17];
  const float* cpe2_b  = (const float*)d_in[18];
  const float* norm2_g = (const float*)d_in[19];
  const float* norm2_b = (const float*)d_in[20];
  const float* fc1_w   = (const float*)d_in[21];
  const float* fc1_b   = (const float*)d_in[22];
  const float* fc2_w   = (const float*)d_in[23];
  const float* fc2_b   = (const float*)d_in[24];
  float* out = (float*)d_out;

  char* ws = (char*)d_ws;
  size_t off = 0;
  auto alloc = [&](size_t bytes) -> char* {
    char* p = ws + off;
    off = (off + bytes + 255) & ~(size_t)255;
    return p;
  };
  float* cosS   = (float*)alloc(KMAX_ * 4);
  float* sinS   = (float*)alloc(KMAX_ * 4);
  u16* wTactp   = (u16*)alloc((size_t)C_ * C_ * 2);
  u16* wTin     = (u16*)alloc((size_t)C_ * C_ * 2);
  u16* wTqk     = (u16*)alloc((size_t)C2_ * C_ * 2);
  u16* wTout    = (u16*)alloc((size_t)C_ * C_ * 2);
  u16* wTfc1    = (u16*)alloc((size_t)HID_ * C_ * 2);
  u16* wTfc2    = (u16*)alloc((size_t)C_ * HID_ * 2);
  float* kmean  = (float*)alloc((size_t)B_ * C_ * 4);
  u16*   kvb    = (u16*)alloc((size_t)128 * 4096 * 2);      // kv^T bf16 (B-frag layout)
  float* kvpart = (float*)alloc((size_t)512 * 4096 * 4);
  float* zbuf   = (float*)alloc((size_t)BL_ * H_ * 4);
  u16* x1       = (u16*)alloc((size_t)BL_ * C_ * 2);        // shortcut (bf16)
  u16* bufX     = (u16*)alloc((size_t)BL_ * C_ * 2);        // xn / g / xn2
  u16* bufY     = (u16*)alloc((size_t)BL_ * C_ * 2);        // act_res -> x3
  u16* bufW     = (u16*)alloc((size_t)BL_ * C_ * 2);        // xi -> MLP hidden chunk
  u16* bufQ     = (u16*)alloc((size_t)BL_ * C2_ * 2);       // xi0(lo) -> qkb -> x2(lo)
  size_t needed = off;
  if (ws_size < needed) return;   // diagnostic: clean failure instead of OOB fault

  u16* xi0 = bufQ;        // 32MB (lower half)
  u16* qkb = bufQ;        // full 64MB
  u16* x2  = bufQ;        // 32MB (lower half), after qkb dead
  u16* xi  = bufW;
  u16* hb  = bufW;        // MLP hidden chunk (after xi dead)
  u16* actres = bufY;
  u16* x3  = bufY;

  rope_table_kernel<<<1, 512, 0, stream>>>(cosS, sinS);
  transpose_bf16_kernel<<<dim3(C_/32,  C_/32 ), 256, 0, stream>>>(actp_w, wTactp, C_,  C_);
  transpose_bf16_kernel<<<dim3(C_/32,  C_/32 ), 256, 0, stream>>>(in_w,   wTin,   C_,  C_);
  transpose_bf16_kernel<<<dim3(C2_/32, C_/32 ), 256, 0, stream>>>(qk_w,   wTqk,   C_,  C2_);
  transpose_bf16_kernel<<<dim3(C_/32,  C_/32 ), 256, 0, stream>>>(out_w,  wTout,  C_,  C_);
  transpose_bf16_kernel<<<dim3(HID_/32,C_/32 ), 256, 0, stream>>>(fc1_w,  wTfc1,  C_,  HID_);
  transpose_bf16_kernel<<<dim3(C_/32,  HID_/32), 256, 0, stream>>>(fc2_w,  wTfc2,  HID_, C_);
  zerofill_kernel<<<(B_*C_ + 255)/256, 256, 0, stream>>>(kmean, B_*C_);

  // x = x + cpe1(x); shortcut=x1; xn = LN(x)
  cpe_ln_kernel<float><<<BL_, 256, 0, stream>>>(x, cpe1_w, cpe1_b, norm1_g, norm1_b, x1, bufX);
  // act_res = silu(xn @ actp_w + b)
  gemm_bf16<EP_SILU><<<dim3(BL_/128, C_/128), 256, 0, stream>>>(
      bufX, wTactp, actp_b, nullptr, nullptr, actres, BL_, C_, C_);
  // xi0 = xn @ in_w + b
  gemm_bf16<EP_NONE><<<dim3(BL_/128, C_/128), 256, 0, stream>>>(
      bufX, wTin, in_b, nullptr, nullptr, xi0, BL_, C_, C_);
  // xi = silu(dwc(xi0))
  dwconv_silu_kernel<<<BL_, 256, 0, stream>>>(xi0, dwc_w, dwc_b, xi);
  // qkb = elu(xi @ qk_w + b) + 1
  gemm_bf16<EP_ELU1><<<dim3(BL_/128, C2_/128), 256, 0, stream>>>(
      xi, wTqk, qk_b, nullptr, nullptr, qkb, BL_, C2_, C_);
  // kmean, z, kv
  colmean_kernel<<<dim3(32, B_), 256, 0, stream>>>(qkb, kmean);
  z_kernel<<<BL_*H_/256, 256, 0, stream>>>(qkb, kmean, zbuf);
  kv_partial_kernel<<<dim3(128, 4), 256, 0, stream>>>(qkb, xi, cosS, sinS, kvpart);
  kv_reduce_kernel<<<128, 256, 0, stream>>>(kvpart, kvb);
  // attn (MFMA) + lepe + gating -> g (bf16, bufX overwrites xn)
  attn_kernel<<<dim3(16, B_, H_), 256, 0, stream>>>(
      qkb, xi, kvb, zbuf, cosS, sinS, lepe_w, lepe_b, actres, bufX);
  // x2 = x1 + g @ out_w + b   (bf16, into bufQ lower half; qkb dead)
  gemm_bf16<EP_RES_BF><<<dim3(BL_/128, C_/128), 256, 0, stream>>>(
      bufX, wTout, out_b, x1, nullptr, x2, BL_, C_, C_);
  // x3 = x2 + cpe2(x2); xn2 = LN2(x3)
  cpe_ln_kernel<u16><<<BL_, 256, 0, stream>>>(x2, cpe2_w, cpe2_b, norm2_g, norm2_b, x3, bufX);
  // MLP in 4 row-chunks of 4096 (hidden chunk lives in bufW; xi dead)
  for (int m = 0; m < 4; ++m){
    size_t ro = (size_t)m * 4096;
    gemm_bf16<EP_GELU><<<dim3(32, HID_/128), 256, 0, stream>>>(
        bufX + ro * C_, wTfc1, fc1_b, nullptr, nullptr, hb, 4096, HID_, C_);
    gemm_bf16<EP_RES_F32><<<dim3(32, C_/128), 256, 0, stream>>>(
        hb, wTfc2, fc2_b, x3 + ro * C_, out + ro * C_, nullptr, 4096, C_, HID_);
  }
}

// Round 8
// 1323.726 us; speedup vs baseline: 1.2073x; 1.1147x over previous
//
#include <hip/hip_runtime.h>
#include <hip/hip_bf16.h>
#include <cstdint>

#define B_    8
#define L_    2048
#define C_    1024
#define H_    16
#define D_    64
#define BL_   16384
#define C2_   2048
#define HID_  4096
#define KMAX_ 512

typedef unsigned short u16;
typedef unsigned int   u32;
typedef __attribute__((ext_vector_type(8))) short short8;   // 8 bf16 (4 VGPRs)
typedef __attribute__((ext_vector_type(4))) float f32x4;

__device__ __forceinline__ u16 f2bf(float f){
  u32 u = __float_as_uint(f);
  u += 0x7fffu + ((u >> 16) & 1u);      // RNE; inputs finite
  return (u16)(u >> 16);
}
__device__ __forceinline__ float bf2f(u16 v){
  return __uint_as_float(((u32)v) << 16);
}
// async global->LDS, 16B per lane; dest = wave-uniform base + lane*16
__device__ __forceinline__ void gld16(const void* g, void* l){
  __builtin_amdgcn_global_load_lds((const __attribute__((address_space(1))) u32*)g,
                                   (__attribute__((address_space(3))) u32*)l, 16, 0, 0);
}

// ---------------- zero fill ---------------------------------------------------
__global__ __launch_bounds__(256) void zerofill_kernel(float* __restrict__ p, int n){
  int i = blockIdx.x * 256 + threadIdx.x;
  if (i < n) p[i] = 0.f;
}

// ---------------- rope table: theta = 10000^(-j/512) --------------------------
__global__ void rope_table_kernel(float* __restrict__ cosS, float* __restrict__ sinS){
  int t = threadIdx.x;
  if (t < KMAX_){
    float th = powf(10000.f, -(float)t / (float)KMAX_);
    cosS[t] = cosf(th);
    sinS[t] = sinf(th);
  }
}

// ---------------- f32 (R,Ccol) -> bf16 (Ccol,R) transpose ---------------------
__global__ __launch_bounds__(256) void transpose_bf16_kernel(
    const float* __restrict__ in, u16* __restrict__ out, int R, int Ccol)
{
  __shared__ float tile[32][33];
  int tx = threadIdx.x & 31, ty = threadIdx.x >> 5;   // 32 x 8
  int c = blockIdx.x * 32 + tx;
  #pragma unroll
  for (int i = 0; i < 4; ++i){
    int r = blockIdx.y * 32 + ty + i * 8;
    tile[ty + i * 8][tx] = in[(size_t)r * Ccol + c];
  }
  __syncthreads();
  int rr = blockIdx.y * 32 + tx;
  #pragma unroll
  for (int i = 0; i < 4; ++i){
    int cc = blockIdx.x * 32 + ty + i * 8;
    out[(size_t)cc * R + rr] = f2bf(tile[tx][ty + i * 8]);
  }
}

// ---------------- depthwise conv3 (+x residual) + LayerNorm -------------------
template<typename T>
__global__ __launch_bounds__(256) void cpe_ln_kernel(
    const T* __restrict__ xin, const float* __restrict__ cw, const float* __restrict__ cb,
    const float* __restrict__ g,   const float* __restrict__ beta,
    u16* __restrict__ xout, u16* __restrict__ xnout)
{
  int bl = blockIdx.x;
  int l  = bl & (L_ - 1);
  const T* xr = xin + (size_t)bl * C_;
  int t = threadIdx.x;
  float vals[4];
  float s = 0.f, ss = 0.f;
  #pragma unroll
  for (int i = 0; i < 4; ++i){
    int c = t + i * 256;
    float xm = (l > 0)      ? (float)xr[c - C_] : 0.f;
    float x0 = (float)xr[c];
    float xp = (l < L_ - 1) ? (float)xr[c + C_] : 0.f;
    float v = x0 + xm * cw[c*3] + x0 * cw[c*3+1] + xp * cw[c*3+2] + cb[c];
    vals[i] = v; s += v; ss += v * v;
  }
  int lane = t & 63, w = t >> 6;
  #pragma unroll
  for (int o = 32; o > 0; o >>= 1){ s += __shfl_down(s, o); ss += __shfl_down(ss, o); }
  __shared__ float red[8];
  __shared__ float sh[2];
  if (lane == 0){ red[w] = s; red[4 + w] = ss; }
  __syncthreads();
  if (t == 0){
    float S  = red[0] + red[1] + red[2] + red[3];
    float SS = red[4] + red[5] + red[6] + red[7];
    float mu = S * (1.f / C_);
    float var = SS * (1.f / C_) - mu * mu;
    sh[0] = mu; sh[1] = rsqrtf(var + 1e-5f);
  }
  __syncthreads();
  float mu = sh[0], inv = sh[1];
  #pragma unroll
  for (int i = 0; i < 4; ++i){
    int c = t + i * 256;
    float xn = (vals[i] - mu) * inv * g[c] + beta[c];
    xout[(size_t)bl * C_ + c]  = f2bf(vals[i]);
    xnout[(size_t)bl * C_ + c] = f2bf(xn);
  }
}
template<> __global__ __launch_bounds__(256) void cpe_ln_kernel<u16>(
    const u16* __restrict__ xin, const float* __restrict__ cw, const float* __restrict__ cb,
    const float* __restrict__ g,   const float* __restrict__ beta,
    u16* __restrict__ xout, u16* __restrict__ xnout)
{
  int bl = blockIdx.x;
  int l  = bl & (L_ - 1);
  const u16* xr = xin + (size_t)bl * C_;
  int t = threadIdx.x;
  float vals[4];
  float s = 0.f, ss = 0.f;
  #pragma unroll
  for (int i = 0; i < 4; ++i){
    int c = t + i * 256;
    float xm = (l > 0)      ? bf2f(xr[c - C_]) : 0.f;
    float x0 = bf2f(xr[c]);
    float xp = (l < L_ - 1) ? bf2f(xr[c + C_]) : 0.f;
    float v = x0 + xm * cw[c*3] + x0 * cw[c*3+1] + xp * cw[c*3+2] + cb[c];
    vals[i] = v; s += v; ss += v * v;
  }
  int lane = t & 63, w = t >> 6;
  #pragma unroll
  for (int o = 32; o > 0; o >>= 1){ s += __shfl_down(s, o); ss += __shfl_down(ss, o); }
  __shared__ float red[8];
  __shared__ float sh[2];
  if (lane == 0){ red[w] = s; red[4 + w] = ss; }
  __syncthreads();
  if (t == 0){
    float S  = red[0] + red[1] + red[2] + red[3];
    float SS = red[4] + red[5] + red[6] + red[7];
    float mu = S * (1.f / C_);
    float var = SS * (1.f / C_) - mu * mu;
    sh[0] = mu; sh[1] = rsqrtf(var + 1e-5f);
  }
  __syncthreads();
  float mu = sh[0], inv = sh[1];
  #pragma unroll
  for (int i = 0; i < 4; ++i){
    int c = t + i * 256;
    float xn = (vals[i] - mu) * inv * g[c] + beta[c];
    xout[(size_t)bl * C_ + c]  = f2bf(vals[i]);
    xnout[(size_t)bl * C_ + c] = f2bf(xn);
  }
}

// ---------------- depthwise conv3 + bias + silu (bf16 in -> bf16 out) --------
__global__ __launch_bounds__(256) void dwconv_silu_kernel(
    const u16* __restrict__ xin, const float* __restrict__ w, const float* __restrict__ bias,
    u16* __restrict__ xb)
{
  int bl = blockIdx.x;
  int l  = bl & (L_ - 1);
  const u16* xr = xin + (size_t)bl * C_;
  int t = threadIdx.x;
  #pragma unroll
  for (int i = 0; i < 4; ++i){
    int c = t + i * 256;
    float xm = (l > 0)      ? bf2f(xr[c - C_]) : 0.f;
    float x0 = bf2f(xr[c]);
    float xp = (l < L_ - 1) ? bf2f(xr[c + C_]) : 0.f;
    float v = xm * w[c*3] + x0 * w[c*3+1] + xp * w[c*3+2] + bias[c];
    v = v / (1.f + expf(-v));
    xb[(size_t)bl * C_ + c] = f2bf(v);
  }
}

// ---------------- column mean of k-half of qkb -> kmean[b][c] ----------------
__global__ __launch_bounds__(256) void colmean_kernel(
    const u16* __restrict__ qkb, float* __restrict__ kmean)
{
  int chunk = blockIdx.x, b = blockIdx.y;
  int l0 = chunk * 64;
  int t = threadIdx.x;
  #pragma unroll
  for (int i = 0; i < 4; ++i){
    int c = t + i * 256;
    float s = 0.f;
    for (int r = 0; r < 64; ++r)
      s += bf2f(qkb[((size_t)(b * L_ + l0 + r)) * C2_ + C_ + c]);
    atomicAdd(&kmean[b * C_ + c], s * (1.f / (float)L_));
  }
}

// ---------------- z[row*16+h] = 1/(q_h . kmean_h + 1e-6) ---------------------
__global__ __launch_bounds__(256) void z_kernel(
    const u16* __restrict__ qkb, const float* __restrict__ kmean,
    float* __restrict__ zg)
{
  int idx = blockIdx.x * 256 + threadIdx.x;   // row*16 + h
  int row = idx >> 4, h = idx & 15;
  int b = row >> 11;
  const u32* qp = (const u32*)(qkb + (size_t)row * C2_ + h * 64);
  const float2* kp = (const float2*)(kmean + b * C_ + h * 64);
  float dot = 0.f;
  #pragma unroll
  for (int i = 0; i < 32; ++i){
    u32 q2 = qp[i]; float2 k2 = kp[i];
    dot += bf2f((u16)(q2 & 0xffff)) * k2.x + bf2f((u16)(q2 >> 16)) * k2.y;
  }
  zg[idx] = 1.f / (dot + 1e-6f);
}

// ---------------- kv partial: per (b,h,chunk) accumulate k_rope ⊗ v ----------
__global__ __launch_bounds__(256) void kv_partial_kernel(
    const u16* __restrict__ qkb, const u16* __restrict__ xi,
    const float* __restrict__ cosS, const float* __restrict__ sinS,
    float* __restrict__ part)
{
  int bh = blockIdx.x, cy = blockIdx.y;
  int b = bh >> 4, h = bh & 15;
  __shared__ float kl[8][64];
  __shared__ float vl[8][64];
  int t = threadIdx.x;
  int rs = t >> 5, j = t & 31;          // staging role: row, pair
  int d  = t >> 2, e0 = (t & 3) << 4;   // compute role
  float cj = cosS[h * 32 + j], sj = sinS[h * 32 + j];
  float acc[16];
  #pragma unroll
  for (int e = 0; e < 16; ++e) acc[e] = 0.f;
  int l0 = cy * 512;
  for (int it = 0; it < 64; ++it){
    int l = l0 + it * 8 + rs;
    u32 kp = *(const u32*)(qkb + ((size_t)(b * L_ + l)) * C2_ + C_ + h * 64 + 2 * j);
    float k0 = bf2f((u16)(kp & 0xffff)), k1 = bf2f((u16)(kp >> 16));
    kl[rs][2*j]   = k0 * cj - k1 * sj;
    kl[rs][2*j+1] = k0 * sj + k1 * cj;
    u32 vp = *(const u32*)(xi + ((size_t)(b * L_ + l)) * C_ + h * 64 + 2 * j);
    vl[rs][2*j]   = bf2f((u16)(vp & 0xffff));
    vl[rs][2*j+1] = bf2f((u16)(vp >> 16));
    __syncthreads();
    #pragma unroll
    for (int r = 0; r < 8; ++r){
      float kd = kl[r][d];
      #pragma unroll
      for (int e = 0; e < 16; ++e) acc[e] += kd * vl[r][e0 + e];
    }
    __syncthreads();
  }
  float* po = part + ((size_t)(bh * 4 + cy)) * 4096 + d * 64 + e0;
  #pragma unroll
  for (int e = 0; e < 16; ++e) po[e] = acc[e];
}

// reduce partials -> kvb bf16 TRANSPOSED [bh][e*64+d] (B-operand layout for MFMA)
__global__ __launch_bounds__(256) void kv_reduce_kernel(
    const float* __restrict__ part, u16* __restrict__ kvb)
{
  int bh = blockIdx.x;
  int t = threadIdx.x;
  #pragma unroll
  for (int i = 0; i < 16; ++i){
    int o = t + i * 256;
    int d = o >> 6, e = o & 63;
    float s = 0.f;
    #pragma unroll
    for (int cy = 0; cy < 4; ++cy)
      s += part[((size_t)(bh * 4 + cy)) * 4096 + o];
    kvb[(size_t)bh * 4096 + e * 64 + d] = f2bf(s * (1.f / (float)L_));
  }
}

// ---------------- fused attention epilogue (MFMA) ----------------------------
__global__ __launch_bounds__(256, 4) void attn_kernel(
    const u16* __restrict__ qkb, const u16* __restrict__ xi,
    const u16* __restrict__ kvb, const float* __restrict__ zg,
    const float* __restrict__ cosS, const float* __restrict__ sinS,
    const float* __restrict__ lw,  const float* __restrict__ lb,
    const u16* __restrict__ actres, u16* __restrict__ gout)
{
  int rc = blockIdx.x, b = blockIdx.y, h = blockIdx.z;
  __shared__ u16 qs[64 * 64];          // 8 KB, 128B rows, XOR-swizzled
  int t = threadIdx.x;
  int lane = t & 63, w = t >> 6;
  int bh = b * H_ + h;
  short8 bq[4][2];
  #pragma unroll
  for (int ni = 0; ni < 4; ++ni)
    #pragma unroll
    for (int kf = 0; kf < 2; ++kf)
      bq[ni][kf] = *(const short8*)(kvb + (size_t)bh * 4096 +
                     (ni * 16 + (lane & 15)) * 64 + kf * 32 + (lane >> 4) * 8);
  int js = t & 31;
  float cj = cosS[h * 32 + js], sj = sinS[h * 32 + js];
  float w0[4], w1[4], w2[4], bb[4];
  #pragma unroll
  for (int ni = 0; ni < 4; ++ni){
    int c = h * 64 + ni * 16 + (lane & 15);
    w0[ni] = lw[c*3]; w1[ni] = lw[c*3+1]; w2[ni] = lw[c*3+2]; bb[ni] = lb[c];
  }
  for (int ch = 0; ch < 2; ++ch){
    int n0 = rc * 128 + ch * 64;
    #pragma unroll
    for (int i = 0; i < 8; ++i){       // stage 64 roped rows as bf16
      int id = t + i * 256;
      int r = id >> 5;                 // pair index == js (low 5 bits)
      u32 q2 = *(const u32*)(qkb + ((size_t)(b * L_ + n0 + r)) * C2_ + h * 64 + 2 * js);
      float q0 = bf2f((u16)(q2 & 0xffff)), q1 = bf2f((u16)(q2 >> 16));
      u32 pk = (u32)f2bf(q0 * cj - q1 * sj) | ((u32)f2bf(q0 * sj + q1 * cj) << 16);
      *(u32*)((char*)qs + r * 128 + ((4 * js) ^ ((r & 7) << 4))) = pk;
    }
    __syncthreads();
    int arow = w * 16 + (lane & 15);
    short8 af0 = *(const short8*)((char*)qs + arow * 128 + ((     (lane >> 4) * 16) ^ ((arow & 7) << 4)));
    short8 af1 = *(const short8*)((char*)qs + arow * 128 + ((64 + (lane >> 4) * 16) ^ ((arow & 7) << 4)));
    f32x4 acc[4] = {};
    #pragma unroll
    for (int ni = 0; ni < 4; ++ni){
      acc[ni] = __builtin_amdgcn_mfma_f32_16x16x32_bf16(af0, bq[ni][0], acc[ni], 0, 0, 0);
      acc[ni] = __builtin_amdgcn_mfma_f32_16x16x32_bf16(af1, bq[ni][1], acc[ni], 0, 0, 0);
    }
    #pragma unroll
    for (int ni = 0; ni < 4; ++ni){
      int c = h * 64 + ni * 16 + (lane & 15);
      #pragma unroll
      for (int r = 0; r < 4; ++r){
        int n = n0 + w * 16 + (lane >> 4) * 4 + r;
        size_t row = (size_t)b * L_ + n;
        float attnv = acc[ni][r] * zg[(row << 4) + h];
        float vm = (n > 0)      ? bf2f(xi[(row - 1) * C_ + c]) : 0.f;
        float v0 = bf2f(xi[row * C_ + c]);
        float vp = (n < L_ - 1) ? bf2f(xi[(row + 1) * C_ + c]) : 0.f;
        float gval = (attnv + vm * w0[ni] + v0 * w1[ni] + vp * w2[ni] + bb[ni]) * bf2f(actres[row * C_ + c]);
        gout[row * C_ + c] = f2bf(gval);
      }
    }
    __syncthreads();
  }
}

// ---------------- bf16 MFMA GEMM, 128x128 tile, BK=64, templated epilogue ----
// staging via global_load_lds w=16: linear LDS dest + inverse-swizzled global src
enum { EP_SILU = 0, EP_NONE = 1, EP_ELU1 = 2, EP_RES_BF = 3, EP_GELU = 4, EP_RES_F32 = 5 };

template<int EP>
__global__ __launch_bounds__(256) void gemm_bf16(
    const u16* __restrict__ A,    // M x K bf16 row-major
    const u16* __restrict__ Bt,   // N x K bf16 row-major (pre-transposed weight)
    const float* __restrict__ bias,
    const u16* __restrict__ res,  // bf16 residual (EP_RES_*)
    float* __restrict__ outF, u16* __restrict__ outB,
    int M, int N, int K)
{
  __shared__ u16 As[128 * 64];
  __shared__ u16 Bs[128 * 64];
  const int t = threadIdx.x;
  const int m0 = blockIdx.x * 128;
  const int n0 = blockIdx.y * 128;
  const int lane = t & 63, w = t >> 6;
  const int wm = (w >> 1) * 64, wn = (w & 1) * 64;
  f32x4 acc[4][4] = {};
  const int ktiles = K >> 6;
  // per-thread staging geometry (constant across K-tiles)
  const int sidx = t;                       // chunk id base; i adds 256
  for (int kt = 0; kt < ktiles; ++kt){
    const u16* Ab = A  + (size_t)m0 * K + kt * 64;
    const u16* Bb = Bt + (size_t)n0 * K + kt * 64;
    #pragma unroll
    for (int i = 0; i < 4; ++i){
      int idx = sidx + i * 256;
      int row = idx >> 3, k8 = idx & 7;
      int srcoff = row * K + ((k8 * 8) ^ ((row & 7) << 3));  // pre-swizzled source
      int wb = (i * 256 + (t & 192)) * 8;                    // wave-uniform LDS base (u16 elems)
      gld16(Ab + srcoff, &As[wb]);
      gld16(Bb + srcoff, &Bs[wb]);
    }
    __syncthreads();   // compiler drains vmcnt before s_barrier
    #pragma unroll
    for (int ks = 0; ks < 2; ++ks){
      short8 af[4], bfr[4];
      int kk = ks * 32 + ((lane >> 4) << 3);
      #pragma unroll
      for (int mi = 0; mi < 4; ++mi){
        int row = wm + mi * 16 + (lane & 15);
        af[mi] = *(const short8*)(&As[row * 64 + (kk ^ ((row & 7) << 3))]);
      }
      #pragma unroll
      for (int ni = 0; ni < 4; ++ni){
        int row = wn + ni * 16 + (lane & 15);
        bfr[ni] = *(const short8*)(&Bs[row * 64 + (kk ^ ((row & 7) << 3))]);
      }
      #pragma unroll
      for (int mi = 0; mi < 4; ++mi)
        #pragma unroll
        for (int ni = 0; ni < 4; ++ni)
          acc[mi][ni] = __builtin_amdgcn_mfma_f32_16x16x32_bf16(af[mi], bfr[ni], acc[mi][ni], 0, 0, 0);
    }
    __syncthreads();
  }
  // epilogue: D row = (lane>>4)*4 + reg, col = lane&15
  #pragma unroll
  for (int mi = 0; mi < 4; ++mi){
    #pragma unroll
    for (int ni = 0; ni < 4; ++ni){
      int gmb = m0 + wm + mi * 16 + ((lane >> 4) << 2);
      int gn  = n0 + wn + ni * 16 + (lane & 15);
      float bv = bias[gn];
      #pragma unroll
      for (int r = 0; r < 4; ++r){
        int gm = gmb + r;
        float v = acc[mi][ni][r] + bv;
        size_t o = (size_t)gm * N + gn;
        if (EP == EP_SILU)      outB[o] = f2bf(v / (1.f + expf(-v)));
        else if (EP == EP_NONE) outB[o] = f2bf(v);
        else if (EP == EP_ELU1) outB[o] = f2bf((v > 0.f) ? (v + 1.f) : expf(v));
        else if (EP == EP_RES_BF) outB[o] = f2bf(v + bf2f(res[o]));
        else if (EP == EP_GELU) outB[o] = f2bf(0.5f * v * (1.f + erff(v * 0.70710678118f)));
        else if (EP == EP_RES_F32) outF[o] = v + bf2f(res[o]);
      }
    }
  }
}

// ------------------------------- launcher ------------------------------------
extern "C" void kernel_launch(void* const* d_in, const int* in_sizes, int n_in,
                              void* d_out, int out_size, void* d_ws, size_t ws_size,
                              hipStream_t stream)
{
  const float* x       = (const float*)d_in[0];
  const float* cpe1_w  = (const float*)d_in[1];
  const float* cpe1_b  = (const float*)d_in[2];
  const float* norm1_g = (const float*)d_in[3];
  const float* norm1_b = (const float*)d_in[4];
  const float* in_w    = (const float*)d_in[5];
  const float* in_b    = (const float*)d_in[6];
  const float* actp_w  = (const float*)d_in[7];
  const float* actp_b  = (const float*)d_in[8];
  const float* dwc_w   = (const float*)d_in[9];
  const float* dwc_b   = (const float*)d_in[10];
  const float* qk_w    = (const float*)d_in[11];
  const float* qk_b    = (const float*)d_in[12];
  const float* lepe_w  = (const float*)d_in[13];
  const float* lepe_b  = (const float*)d_in[14];
  const float* out_w   = (const float*)d_in[15];
  const float* out_b   = (const float*)d_in[16];
  const float* cpe2_w  = (const float*)d_in[17];
  const float* cpe2_b  = (const float*)d_in[18];
  const float* norm2_g = (const float*)d_in[19];
  const float* norm2_b = (const float*)d_in[20];
  const float* fc1_w   = (const float*)d_in[21];
  const float* fc1_b   = (const float*)d_in[22];
  const float* fc2_w   = (const float*)d_in[23];
  const float* fc2_b   = (const float*)d_in[24];
  float* out = (float*)d_out;

  char* ws = (char*)d_ws;
  size_t off = 0;
  auto alloc = [&](size_t bytes) -> char* {
    char* p = ws + off;
    off = (off + bytes + 255) & ~(size_t)255;
    return p;
  };
  float* cosS   = (float*)alloc(KMAX_ * 4);
  float* sinS   = (float*)alloc(KMAX_ * 4);
  u16* wTactp   = (u16*)alloc((size_t)C_ * C_ * 2);
  u16* wTin     = (u16*)alloc((size_t)C_ * C_ * 2);
  u16* wTqk     = (u16*)alloc((size_t)C2_ * C_ * 2);
  u16* wTout    = (u16*)alloc((size_t)C_ * C_ * 2);
  u16* wTfc1    = (u16*)alloc((size_t)HID_ * C_ * 2);
  u16* wTfc2    = (u16*)alloc((size_t)C_ * HID_ * 2);
  float* kmean  = (float*)alloc((size_t)B_ * C_ * 4);
  u16*   kvb    = (u16*)alloc((size_t)128 * 4096 * 2);      // kv^T bf16 (B-frag layout)
  float* kvpart = (float*)alloc((size_t)512 * 4096 * 4);
  float* zbuf   = (float*)alloc((size_t)BL_ * H_ * 4);
  u16* x1       = (u16*)alloc((size_t)BL_ * C_ * 2);        // shortcut (bf16)
  u16* bufX     = (u16*)alloc((size_t)BL_ * C_ * 2);        // xn / g / xn2
  u16* bufY     = (u16*)alloc((size_t)BL_ * C_ * 2);        // act_res -> x3
  u16* bufW     = (u16*)alloc((size_t)BL_ * C_ * 2);        // xi -> MLP hidden chunk
  u16* bufQ     = (u16*)alloc((size_t)BL_ * C2_ * 2);       // xi0(lo) -> qkb -> x2(lo)
  size_t needed = off;
  if (ws_size < needed) return;   // diagnostic: clean failure instead of OOB fault

  u16* xi0 = bufQ;        // 32MB (lower half)
  u16* qkb = bufQ;        // full 64MB
  u16* x2  = bufQ;        // 32MB (lower half), after qkb dead
  u16* xi  = bufW;
  u16* hb  = bufW;        // MLP hidden chunk (after xi dead)
  u16* actres = bufY;
  u16* x3  = bufY;

  rope_table_kernel<<<1, 512, 0, stream>>>(cosS, sinS);
  transpose_bf16_kernel<<<dim3(C_/32,  C_/32 ), 256, 0, stream>>>(actp_w, wTactp, C_,  C_);
  transpose_bf16_kernel<<<dim3(C_/32,  C_/32 ), 256, 0, stream>>>(in_w,   wTin,   C_,  C_);
  transpose_bf16_kernel<<<dim3(C2_/32, C_/32 ), 256, 0, stream>>>(qk_w,   wTqk,   C_,  C2_);
  transpose_bf16_kernel<<<dim3(C_/32,  C_/32 ), 256, 0, stream>>>(out_w,  wTout,  C_,  C_);
  transpose_bf16_kernel<<<dim3(HID_/32,C_/32 ), 256, 0, stream>>>(fc1_w,  wTfc1,  C_,  HID_);
  transpose_bf16_kernel<<<dim3(C_/32,  HID_/32), 256, 0, stream>>>(fc2_w,  wTfc2,  HID_, C_);
  zerofill_kernel<<<(B_*C_ + 255)/256, 256, 0, stream>>>(kmean, B_*C_);

  // x = x + cpe1(x); shortcut=x1; xn = LN(x)
  cpe_ln_kernel<float><<<BL_, 256, 0, stream>>>(x, cpe1_w, cpe1_b, norm1_g, norm1_b, x1, bufX);
  // act_res = silu(xn @ actp_w + b)
  gemm_bf16<EP_SILU><<<dim3(BL_/128, C_/128), 256, 0, stream>>>(
      bufX, wTactp, actp_b, nullptr, nullptr, actres, BL_, C_, C_);
  // xi0 = xn @ in_w + b
  gemm_bf16<EP_NONE><<<dim3(BL_/128, C_/128), 256, 0, stream>>>(
      bufX, wTin, in_b, nullptr, nullptr, xi0, BL_, C_, C_);
  // xi = silu(dwc(xi0))
  dwconv_silu_kernel<<<BL_, 256, 0, stream>>>(xi0, dwc_w, dwc_b, xi);
  // qkb = elu(xi @ qk_w + b) + 1
  gemm_bf16<EP_ELU1><<<dim3(BL_/128, C2_/128), 256, 0, stream>>>(
      xi, wTqk, qk_b, nullptr, nullptr, qkb, BL_, C2_, C_);
  // kmean, z, kv
  colmean_kernel<<<dim3(32, B_), 256, 0, stream>>>(qkb, kmean);
  z_kernel<<<BL_*H_/256, 256, 0, stream>>>(qkb, kmean, zbuf);
  kv_partial_kernel<<<dim3(128, 4), 256, 0, stream>>>(qkb, xi, cosS, sinS, kvpart);
  kv_reduce_kernel<<<128, 256, 0, stream>>>(kvpart, kvb);
  // attn (MFMA) + lepe + gating -> g (bf16, bufX overwrites xn)
  attn_kernel<<<dim3(16, B_, H_), 256, 0, stream>>>(
      qkb, xi, kvb, zbuf, cosS, sinS, lepe_w, lepe_b, actres, bufX);
  // x2 = x1 + g @ out_w + b   (bf16, into bufQ lower half; qkb dead)
  gemm_bf16<EP_RES_BF><<<dim3(BL_/128, C_/128), 256, 0, stream>>>(
      bufX, wTout, out_b, x1, nullptr, x2, BL_, C_, C_);
  // x3 = x2 + cpe2(x2); xn2 = LN2(x3)
  cpe_ln_kernel<u16><<<BL_, 256, 0, stream>>>(x2, cpe2_w, cpe2_b, norm2_g, norm2_b, x3, bufX);
  // MLP in 4 row-chunks of 4096 (hidden chunk lives in bufW; xi dead)
  for (int m = 0; m < 4; ++m){
    size_t ro = (size_t)m * 4096;
    gemm_bf16<EP_GELU><<<dim3(32, HID_/128), 256, 0, stream>>>(
        bufX + ro * C_, wTfc1, fc1_b, nullptr, nullptr, hb, 4096, HID_, C_);
    gemm_bf16<EP_RES_F32><<<dim3(32, C_/128), 256, 0, stream>>>(
        hb, wTfc2, fc2_b, x3 + ro * C_, out + ro * C_, nullptr, 4096, C_, HID_);
  }
}

// Round 9
// 1259.760 us; speedup vs baseline: 1.2686x; 1.0508x over previous
//
#include <hip/hip_runtime.h>
#include <hip/hip_bf16.h>
#include <cstdint>

#define B_    8
#define L_    2048
#define C_    1024
#define H_    16
#define D_    64
#define BL_   16384
#define C2_   2048
#define HID_  4096
#define KMAX_ 512

typedef unsigned short u16;
typedef unsigned int   u32;
typedef __attribute__((ext_vector_type(8))) short short8;    // 8 bf16 (4 VGPRs)
typedef __attribute__((ext_vector_type(4))) float f32x4;
typedef __attribute__((ext_vector_type(16))) float f32x16;

__device__ __forceinline__ u16 f2bf(float f){
  u32 u = __float_as_uint(f);
  u += 0x7fffu + ((u >> 16) & 1u);      // RNE; inputs finite
  return (u16)(u >> 16);
}
__device__ __forceinline__ float bf2f(u16 v){
  return __uint_as_float(((u32)v) << 16);
}
// async global->LDS, 16B per lane; dest = wave-uniform base + lane*16
__device__ __forceinline__ void gld16(const void* g, void* l){
  __builtin_amdgcn_global_load_lds((const __attribute__((address_space(1))) u32*)g,
                                   (__attribute__((address_space(3))) u32*)l, 16, 0, 0);
}

// ---------------- zero fill ---------------------------------------------------
__global__ __launch_bounds__(256) void zerofill_kernel(float* __restrict__ p, int n){
  int i = blockIdx.x * 256 + threadIdx.x;
  if (i < n) p[i] = 0.f;
}

// ---------------- concat bias [actp_b | in_b] ---------------------------------
__global__ __launch_bounds__(256) void concat_bias_kernel(
    const float* __restrict__ b0, const float* __restrict__ b1, float* __restrict__ o){
  int i = blockIdx.x * 256 + threadIdx.x;
  if (i < C_) o[i] = b0[i];
  else if (i < C2_) o[i] = b1[i - C_];
}

// ---------------- rope table: theta = 10000^(-j/512) --------------------------
__global__ void rope_table_kernel(float* __restrict__ cosS, float* __restrict__ sinS){
  int t = threadIdx.x;
  if (t < KMAX_){
    float th = powf(10000.f, -(float)t / (float)KMAX_);
    cosS[t] = cosf(th);
    sinS[t] = sinf(th);
  }
}

// ---------------- f32 (R,Ccol) -> bf16 (Ccol,R) transpose ---------------------
__global__ __launch_bounds__(256) void transpose_bf16_kernel(
    const float* __restrict__ in, u16* __restrict__ out, int R, int Ccol)
{
  __shared__ float tile[32][33];
  int tx = threadIdx.x & 31, ty = threadIdx.x >> 5;   // 32 x 8
  int c = blockIdx.x * 32 + tx;
  #pragma unroll
  for (int i = 0; i < 4; ++i){
    int r = blockIdx.y * 32 + ty + i * 8;
    tile[ty + i * 8][tx] = in[(size_t)r * Ccol + c];
  }
  __syncthreads();
  int rr = blockIdx.y * 32 + tx;
  #pragma unroll
  for (int i = 0; i < 4; ++i){
    int cc = blockIdx.x * 32 + ty + i * 8;
    out[(size_t)cc * R + rr] = f2bf(tile[tx][ty + i * 8]);
  }
}

// ---------------- depthwise conv3 (+x residual) + LayerNorm -------------------
template<typename T>
__global__ __launch_bounds__(256) void cpe_ln_kernel(
    const T* __restrict__ xin, const float* __restrict__ cw, const float* __restrict__ cb,
    const float* __restrict__ g,   const float* __restrict__ beta,
    u16* __restrict__ xout, u16* __restrict__ xnout)
{
  int bl = blockIdx.x;
  int l  = bl & (L_ - 1);
  const T* xr = xin + (size_t)bl * C_;
  int t = threadIdx.x;
  float vals[4];
  float s = 0.f, ss = 0.f;
  #pragma unroll
  for (int i = 0; i < 4; ++i){
    int c = t + i * 256;
    float xm = (l > 0)      ? (float)xr[c - C_] : 0.f;
    float x0 = (float)xr[c];
    float xp = (l < L_ - 1) ? (float)xr[c + C_] : 0.f;
    float v = x0 + xm * cw[c*3] + x0 * cw[c*3+1] + xp * cw[c*3+2] + cb[c];
    vals[i] = v; s += v; ss += v * v;
  }
  int lane = t & 63, w = t >> 6;
  #pragma unroll
  for (int o = 32; o > 0; o >>= 1){ s += __shfl_down(s, o); ss += __shfl_down(ss, o); }
  __shared__ float red[8];
  __shared__ float sh[2];
  if (lane == 0){ red[w] = s; red[4 + w] = ss; }
  __syncthreads();
  if (t == 0){
    float S  = red[0] + red[1] + red[2] + red[3];
    float SS = red[4] + red[5] + red[6] + red[7];
    float mu = S * (1.f / C_);
    float var = SS * (1.f / C_) - mu * mu;
    sh[0] = mu; sh[1] = rsqrtf(var + 1e-5f);
  }
  __syncthreads();
  float mu = sh[0], inv = sh[1];
  #pragma unroll
  for (int i = 0; i < 4; ++i){
    int c = t + i * 256;
    float xn = (vals[i] - mu) * inv * g[c] + beta[c];
    xout[(size_t)bl * C_ + c]  = f2bf(vals[i]);
    xnout[(size_t)bl * C_ + c] = f2bf(xn);
  }
}
template<> __global__ __launch_bounds__(256) void cpe_ln_kernel<u16>(
    const u16* __restrict__ xin, const float* __restrict__ cw, const float* __restrict__ cb,
    const float* __restrict__ g,   const float* __restrict__ beta,
    u16* __restrict__ xout, u16* __restrict__ xnout)
{
  int bl = blockIdx.x;
  int l  = bl & (L_ - 1);
  const u16* xr = xin + (size_t)bl * C_;
  int t = threadIdx.x;
  float vals[4];
  float s = 0.f, ss = 0.f;
  #pragma unroll
  for (int i = 0; i < 4; ++i){
    int c = t + i * 256;
    float xm = (l > 0)      ? bf2f(xr[c - C_]) : 0.f;
    float x0 = bf2f(xr[c]);
    float xp = (l < L_ - 1) ? bf2f(xr[c + C_]) : 0.f;
    float v = x0 + xm * cw[c*3] + x0 * cw[c*3+1] + xp * cw[c*3+2] + cb[c];
    vals[i] = v; s += v; ss += v * v;
  }
  int lane = t & 63, w = t >> 6;
  #pragma unroll
  for (int o = 32; o > 0; o >>= 1){ s += __shfl_down(s, o); ss += __shfl_down(ss, o); }
  __shared__ float red[8];
  __shared__ float sh[2];
  if (lane == 0){ red[w] = s; red[4 + w] = ss; }
  __syncthreads();
  if (t == 0){
    float S  = red[0] + red[1] + red[2] + red[3];
    float SS = red[4] + red[5] + red[6] + red[7];
    float mu = S * (1.f / C_);
    float var = SS * (1.f / C_) - mu * mu;
    sh[0] = mu; sh[1] = rsqrtf(var + 1e-5f);
  }
  __syncthreads();
  float mu = sh[0], inv = sh[1];
  #pragma unroll
  for (int i = 0; i < 4; ++i){
    int c = t + i * 256;
    float xn = (vals[i] - mu) * inv * g[c] + beta[c];
    xout[(size_t)bl * C_ + c]  = f2bf(vals[i]);
    xnout[(size_t)bl * C_ + c] = f2bf(xn);
  }
}

// ---------------- depthwise conv3 + bias + silu (bf16 in -> bf16 out) --------
__global__ __launch_bounds__(256) void dwconv_silu_kernel(
    const u16* __restrict__ xin, const float* __restrict__ w, const float* __restrict__ bias,
    u16* __restrict__ xb)
{
  int bl = blockIdx.x;
  int l  = bl & (L_ - 1);
  const u16* xr = xin + (size_t)bl * C_;
  int t = threadIdx.x;
  #pragma unroll
  for (int i = 0; i < 4; ++i){
    int c = t + i * 256;
    float xm = (l > 0)      ? bf2f(xr[c - C_]) : 0.f;
    float x0 = bf2f(xr[c]);
    float xp = (l < L_ - 1) ? bf2f(xr[c + C_]) : 0.f;
    float v = xm * w[c*3] + x0 * w[c*3+1] + xp * w[c*3+2] + bias[c];
    v = v / (1.f + expf(-v));
    xb[(size_t)bl * C_ + c] = f2bf(v);
  }
}

// ---------------- column mean of k-half of qkb -> kmean[b][c] ----------------
__global__ __launch_bounds__(256) void colmean_kernel(
    const u16* __restrict__ qkb, float* __restrict__ kmean)
{
  int chunk = blockIdx.x, b = blockIdx.y;
  int l0 = chunk * 64;
  int t = threadIdx.x;
  #pragma unroll
  for (int i = 0; i < 4; ++i){
    int c = t + i * 256;
    float s = 0.f;
    for (int r = 0; r < 64; ++r)
      s += bf2f(qkb[((size_t)(b * L_ + l0 + r)) * C2_ + C_ + c]);
    atomicAdd(&kmean[b * C_ + c], s * (1.f / (float)L_));
  }
}

// ---------------- z[row*16+h] = 1/(q_h . kmean_h + 1e-6) ---------------------
__global__ __launch_bounds__(256) void z_kernel(
    const u16* __restrict__ qkb, const float* __restrict__ kmean,
    float* __restrict__ zg)
{
  int idx = blockIdx.x * 256 + threadIdx.x;   // row*16 + h
  int row = idx >> 4, h = idx & 15;
  int b = row >> 11;
  const u32* qp = (const u32*)(qkb + (size_t)row * C2_ + h * 64);
  const float2* kp = (const float2*)(kmean + b * C_ + h * 64);
  float dot = 0.f;
  #pragma unroll
  for (int i = 0; i < 32; ++i){
    u32 q2 = qp[i]; float2 k2 = kp[i];
    dot += bf2f((u16)(q2 & 0xffff)) * k2.x + bf2f((u16)(q2 >> 16)) * k2.y;
  }
  zg[idx] = 1.f / (dot + 1e-6f);
}

// ---------------- kv partial: per (b,h,chunk) accumulate k_rope ⊗ v ----------
__global__ __launch_bounds__(256) void kv_partial_kernel(
    const u16* __restrict__ qkb, const u16* __restrict__ xi,
    const float* __restrict__ cosS, const float* __restrict__ sinS,
    float* __restrict__ part)
{
  int bh = blockIdx.x, cy = blockIdx.y;
  int b = bh >> 4, h = bh & 15;
  __shared__ float kl[8][64];
  __shared__ float vl[8][64];
  int t = threadIdx.x;
  int rs = t >> 5, j = t & 31;          // staging role: row, pair
  int d  = t >> 2, e0 = (t & 3) << 4;   // compute role
  float cj = cosS[h * 32 + j], sj = sinS[h * 32 + j];
  float acc[16];
  #pragma unroll
  for (int e = 0; e < 16; ++e) acc[e] = 0.f;
  int l0 = cy * 512;
  for (int it = 0; it < 64; ++it){
    int l = l0 + it * 8 + rs;
    u32 kp = *(const u32*)(qkb + ((size_t)(b * L_ + l)) * C2_ + C_ + h * 64 + 2 * j);
    float k0 = bf2f((u16)(kp & 0xffff)), k1 = bf2f((u16)(kp >> 16));
    kl[rs][2*j]   = k0 * cj - k1 * sj;
    kl[rs][2*j+1] = k0 * sj + k1 * cj;
    u32 vp = *(const u32*)(xi + ((size_t)(b * L_ + l)) * C_ + h * 64 + 2 * j);
    vl[rs][2*j]   = bf2f((u16)(vp & 0xffff));
    vl[rs][2*j+1] = bf2f((u16)(vp >> 16));
    __syncthreads();
    #pragma unroll
    for (int r = 0; r < 8; ++r){
      float kd = kl[r][d];
      #pragma unroll
      for (int e = 0; e < 16; ++e) acc[e] += kd * vl[r][e0 + e];
    }
    __syncthreads();
  }
  float* po = part + ((size_t)(bh * 4 + cy)) * 4096 + d * 64 + e0;
  #pragma unroll
  for (int e = 0; e < 16; ++e) po[e] = acc[e];
}

// reduce partials -> kvb bf16 TRANSPOSED [bh][e*64+d] (B-operand layout for MFMA)
__global__ __launch_bounds__(256) void kv_reduce_kernel(
    const float* __restrict__ part, u16* __restrict__ kvb)
{
  int bh = blockIdx.x;
  int t = threadIdx.x;
  #pragma unroll
  for (int i = 0; i < 16; ++i){
    int o = t + i * 256;
    int d = o >> 6, e = o & 63;
    float s = 0.f;
    #pragma unroll
    for (int cy = 0; cy < 4; ++cy)
      s += part[((size_t)(bh * 4 + cy)) * 4096 + o];
    kvb[(size_t)bh * 4096 + e * 64 + d] = f2bf(s * (1.f / (float)L_));
  }
}

// ---------------- fused attention epilogue (MFMA 16x16, verified) ------------
__global__ __launch_bounds__(256, 4) void attn_kernel(
    const u16* __restrict__ qkb, const u16* __restrict__ xi,
    const u16* __restrict__ kvb, const float* __restrict__ zg,
    const float* __restrict__ cosS, const float* __restrict__ sinS,
    const float* __restrict__ lw,  const float* __restrict__ lb,
    const u16* __restrict__ actres, u16* __restrict__ gout)
{
  int rc = blockIdx.x, b = blockIdx.y, h = blockIdx.z;
  __shared__ u16 qs[64 * 64];          // 8 KB, 128B rows, XOR-swizzled
  int t = threadIdx.x;
  int lane = t & 63, w = t >> 6;
  int bh = b * H_ + h;
  short8 bq[4][2];
  #pragma unroll
  for (int ni = 0; ni < 4; ++ni)
    #pragma unroll
    for (int kf = 0; kf < 2; ++kf)
      bq[ni][kf] = *(const short8*)(kvb + (size_t)bh * 4096 +
                     (ni * 16 + (lane & 15)) * 64 + kf * 32 + (lane >> 4) * 8);
  int js = t & 31;
  float cj = cosS[h * 32 + js], sj = sinS[h * 32 + js];
  float w0[4], w1[4], w2[4], bb[4];
  #pragma unroll
  for (int ni = 0; ni < 4; ++ni){
    int c = h * 64 + ni * 16 + (lane & 15);
    w0[ni] = lw[c*3]; w1[ni] = lw[c*3+1]; w2[ni] = lw[c*3+2]; bb[ni] = lb[c];
  }
  for (int ch = 0; ch < 2; ++ch){
    int n0 = rc * 128 + ch * 64;
    #pragma unroll
    for (int i = 0; i < 8; ++i){       // stage 64 roped rows as bf16
      int id = t + i * 256;
      int r = id >> 5;                 // pair index == js (low 5 bits)
      u32 q2 = *(const u32*)(qkb + ((size_t)(b * L_ + n0 + r)) * C2_ + h * 64 + 2 * js);
      float q0 = bf2f((u16)(q2 & 0xffff)), q1 = bf2f((u16)(q2 >> 16));
      u32 pk = (u32)f2bf(q0 * cj - q1 * sj) | ((u32)f2bf(q0 * sj + q1 * cj) << 16);
      *(u32*)((char*)qs + r * 128 + ((4 * js) ^ ((r & 7) << 4))) = pk;
    }
    __syncthreads();
    int arow = w * 16 + (lane & 15);
    short8 af0 = *(const short8*)((char*)qs + arow * 128 + ((     (lane >> 4) * 16) ^ ((arow & 7) << 4)));
    short8 af1 = *(const short8*)((char*)qs + arow * 128 + ((64 + (lane >> 4) * 16) ^ ((arow & 7) << 4)));
    f32x4 acc[4] = {};
    #pragma unroll
    for (int ni = 0; ni < 4; ++ni){
      acc[ni] = __builtin_amdgcn_mfma_f32_16x16x32_bf16(af0, bq[ni][0], acc[ni], 0, 0, 0);
      acc[ni] = __builtin_amdgcn_mfma_f32_16x16x32_bf16(af1, bq[ni][1], acc[ni], 0, 0, 0);
    }
    #pragma unroll
    for (int ni = 0; ni < 4; ++ni){
      int c = h * 64 + ni * 16 + (lane & 15);
      #pragma unroll
      for (int r = 0; r < 4; ++r){
        int n = n0 + w * 16 + (lane >> 4) * 4 + r;
        size_t row = (size_t)b * L_ + n;
        float attnv = acc[ni][r] * zg[(row << 4) + h];
        float vm = (n > 0)      ? bf2f(xi[(row - 1) * C_ + c]) : 0.f;
        float v0 = bf2f(xi[row * C_ + c]);
        float vp = (n < L_ - 1) ? bf2f(xi[(row + 1) * C_ + c]) : 0.f;
        float gval = (attnv + vm * w0[ni] + v0 * w1[ni] + vp * w2[ni] + bb[ni]) * bf2f(actres[row * C_ + c]);
        gout[row * C_ + c] = f2bf(gval);
      }
    }
    __syncthreads();
  }
}

// ---------------- bf16 MFMA GEMM, 128x128 tile, BK=64, 32x32x16 frags --------
// staging via global_load_lds w=16: linear LDS dest + inverse-swizzled global src
enum { EP_SILU = 0, EP_NONE = 1, EP_ELU1 = 2, EP_RES_BF = 3, EP_GELU = 4, EP_RES_F32 = 5, EP_ACTIN = 6 };

template<int EP>
__global__ __launch_bounds__(256) void gemm_bf16(
    const u16* __restrict__ A,    // M x K bf16 row-major
    const u16* __restrict__ Bt,   // N x K bf16 row-major (pre-transposed weight)
    const float* __restrict__ bias,
    const u16* __restrict__ res,  // bf16 residual (EP_RES_*)
    float* __restrict__ outF, u16* __restrict__ outB, u16* __restrict__ outB2,
    int M, int N, int K)
{
  __shared__ u16 As[128 * 64];
  __shared__ u16 Bs[128 * 64];
  const int t = threadIdx.x;
  const int m0 = blockIdx.x * 128;
  const int n0 = blockIdx.y * 128;
  const int lane = t & 63, w = t >> 6;
  const int wm = (w >> 1) * 64, wn = (w & 1) * 64;
  f32x16 acc00 = {}, acc01 = {}, acc10 = {}, acc11 = {};
  const int ktiles = K >> 6;
  for (int kt = 0; kt < ktiles; ++kt){
    const u16* Ab = A  + (size_t)m0 * K + kt * 64;
    const u16* Bb = Bt + (size_t)n0 * K + kt * 64;
    #pragma unroll
    for (int i = 0; i < 4; ++i){
      int idx = t + i * 256;
      int row = idx >> 3, k8 = idx & 7;
      int srcoff = row * K + ((k8 * 8) ^ ((row & 7) << 3));  // pre-swizzled source
      int wb = (i * 256 + (t & 192)) * 8;                    // wave-uniform LDS base (u16 elems)
      gld16(Ab + srcoff, &As[wb]);
      gld16(Bb + srcoff, &Bs[wb]);
    }
    __syncthreads();   // compiler drains vmcnt before s_barrier
    // 32x32x16 fragments: A row=lane&31, k=(lane>>5)*8+j; B col=lane&31, same k
    const int rA0 = wm + (lane & 31), rA1 = rA0 + 32;
    const int rB0 = wn + (lane & 31), rB1 = rB0 + 32;
    const int sw = (lane & 7) << 3;     // rA&7 == rB&7 == lane&7 (wm,wn,32 ≡ 0 mod 8)
    #pragma unroll
    for (int ks = 0; ks < 4; ++ks){
      int kb = ks * 16 + ((lane >> 5) << 3);
      short8 a0 = *(const short8*)(&As[rA0 * 64 + (kb ^ sw)]);
      short8 a1 = *(const short8*)(&As[rA1 * 64 + (kb ^ sw)]);
      short8 b0 = *(const short8*)(&Bs[rB0 * 64 + (kb ^ sw)]);
      short8 b1 = *(const short8*)(&Bs[rB1 * 64 + (kb ^ sw)]);
      acc00 = __builtin_amdgcn_mfma_f32_32x32x16_bf16(a0, b0, acc00, 0, 0, 0);
      acc01 = __builtin_amdgcn_mfma_f32_32x32x16_bf16(a0, b1, acc01, 0, 0, 0);
      acc10 = __builtin_amdgcn_mfma_f32_32x32x16_bf16(a1, b0, acc10, 0, 0, 0);
      acc11 = __builtin_amdgcn_mfma_f32_32x32x16_bf16(a1, b1, acc11, 0, 0, 0);
    }
    __syncthreads();
  }
  // epilogue. 32x32 C/D: col=lane&31, row=(r&3)+8*(r>>2)+4*(lane>>5)
  const int rbase = (lane >> 5) << 2;
  #pragma unroll
  for (int mi = 0; mi < 2; ++mi){
    #pragma unroll
    for (int ni = 0; ni < 2; ++ni){
      const f32x16& a = (mi == 0) ? (ni == 0 ? acc00 : acc01) : (ni == 0 ? acc10 : acc11);
      int gn = n0 + wn + ni * 32 + (lane & 31);
      float bv = bias[gn];
      #pragma unroll
      for (int r = 0; r < 16; ++r){
        int gm = m0 + wm + mi * 32 + (r & 3) + ((r >> 2) << 3) + rbase;
        float v = a[r] + bv;
        size_t o = (size_t)gm * N + gn;
        if (EP == EP_SILU)      outB[o] = f2bf(v / (1.f + expf(-v)));
        else if (EP == EP_NONE) outB[o] = f2bf(v);
        else if (EP == EP_ELU1) outB[o] = f2bf((v > 0.f) ? (v + 1.f) : expf(v));
        else if (EP == EP_RES_BF) outB[o] = f2bf(v + bf2f(res[o]));
        else if (EP == EP_GELU){
          // tanh-form gelu: v*sigmoid(1.5957691v + 0.0713549v^3); |err|<~1e-3
          float u = v * (1.5957691f + 0.0713549f * v * v);
          outB[o] = f2bf(v / (1.f + expf(-u)));
        }
        else if (EP == EP_RES_F32) outF[o] = v + bf2f(res[o]);
        else if (EP == EP_ACTIN){
          int half = N >> 1;
          if (gn < half) outB[(size_t)gm * half + gn] = f2bf(v / (1.f + expf(-v)));
          else           outB2[(size_t)gm * half + gn - half] = f2bf(v);
        }
      }
    }
  }
}

// ------------------------------- launcher ------------------------------------
extern "C" void kernel_launch(void* const* d_in, const int* in_sizes, int n_in,
                              void* d_out, int out_size, void* d_ws, size_t ws_size,
                              hipStream_t stream)
{
  const float* x       = (const float*)d_in[0];
  const float* cpe1_w  = (const float*)d_in[1];
  const float* cpe1_b  = (const float*)d_in[2];
  const float* norm1_g = (const float*)d_in[3];
  const float* norm1_b = (const float*)d_in[4];
  const float* in_w    = (const float*)d_in[5];
  const float* in_b    = (const float*)d_in[6];
  const float* actp_w  = (const float*)d_in[7];
  const float* actp_b  = (const float*)d_in[8];
  const float* dwc_w   = (const float*)d_in[9];
  const float* dwc_b   = (const float*)d_in[10];
  const float* qk_w    = (const float*)d_in[11];
  const float* qk_b    = (const float*)d_in[12];
  const float* lepe_w  = (const float*)d_in[13];
  const float* lepe_b  = (const float*)d_in[14];
  const float* out_w   = (const float*)d_in[15];
  const float* out_b   = (const float*)d_in[16];
  const float* cpe2_w  = (const float*)d_in[17];
  const float* cpe2_b  = (const float*)d_in[18];
  const float* norm2_g = (const float*)d_in[19];
  const float* norm2_b = (const float*)d_in[20];
  const float* fc1_w   = (const float*)d_in[21];
  const float* fc1_b   = (const float*)d_in[22];
  const float* fc2_w   = (const float*)d_in[23];
  const float* fc2_b   = (const float*)d_in[24];
  float* out = (float*)d_out;

  char* ws = (char*)d_ws;
  size_t off = 0;
  auto alloc = [&](size_t bytes) -> char* {
    char* p = ws + off;
    off = (off + bytes + 255) & ~(size_t)255;
    return p;
  };
  float* cosS   = (float*)alloc(KMAX_ * 4);
  float* sinS   = (float*)alloc(KMAX_ * 4);
  u16* wTai     = (u16*)alloc((size_t)2 * C_ * C_ * 2);     // [actp^T | in^T] contiguous
  u16* wTqk     = (u16*)alloc((size_t)C2_ * C_ * 2);
  u16* wTout    = (u16*)alloc((size_t)C_ * C_ * 2);
  u16* wTfc1    = (u16*)alloc((size_t)HID_ * C_ * 2);
  u16* wTfc2    = (u16*)alloc((size_t)C_ * HID_ * 2);
  float* biasAI = (float*)alloc((size_t)C2_ * 4);
  float* kmean  = (float*)alloc((size_t)B_ * C_ * 4);
  u16*   kvb    = (u16*)alloc((size_t)128 * 4096 * 2);      // kv^T bf16 (B-frag layout)
  float* kvpart = (float*)alloc((size_t)512 * 4096 * 4);
  float* zbuf   = (float*)alloc((size_t)BL_ * H_ * 4);
  u16* x1       = (u16*)alloc((size_t)BL_ * C_ * 2);        // shortcut (bf16)
  u16* bufX     = (u16*)alloc((size_t)BL_ * C_ * 2);        // xn / g / xn2
  u16* bufY     = (u16*)alloc((size_t)BL_ * C_ * 2);        // act_res -> x3
  u16* bufW     = (u16*)alloc((size_t)BL_ * C_ * 2);        // xi -> MLP hidden chunk
  u16* bufQ     = (u16*)alloc((size_t)BL_ * C2_ * 2);       // xi0(lo) -> qkb -> x2(lo)
  size_t needed = off;
  if (ws_size < needed) return;   // diagnostic: clean failure instead of OOB fault

  u16* wTactp = wTai;
  u16* wTin   = wTai + (size_t)C_ * C_;
  u16* xi0 = bufQ;        // 32MB (lower half)
  u16* qkb = bufQ;        // full 64MB
  u16* x2  = bufQ;        // 32MB (lower half), after qkb dead
  u16* xi  = bufW;
  u16* hb  = bufW;        // MLP hidden chunk (after xi dead)
  u16* actres = bufY;
  u16* x3  = bufY;

  rope_table_kernel<<<1, 512, 0, stream>>>(cosS, sinS);
  transpose_bf16_kernel<<<dim3(C_/32,  C_/32 ), 256, 0, stream>>>(actp_w, wTactp, C_,  C_);
  transpose_bf16_kernel<<<dim3(C_/32,  C_/32 ), 256, 0, stream>>>(in_w,   wTin,   C_,  C_);
  transpose_bf16_kernel<<<dim3(C2_/32, C_/32 ), 256, 0, stream>>>(qk_w,   wTqk,   C_,  C2_);
  transpose_bf16_kernel<<<dim3(C_/32,  C_/32 ), 256, 0, stream>>>(out_w,  wTout,  C_,  C_);
  transpose_bf16_kernel<<<dim3(HID_/32,C_/32 ), 256, 0, stream>>>(fc1_w,  wTfc1,  C_,  HID_);
  transpose_bf16_kernel<<<dim3(C_/32,  HID_/32), 256, 0, stream>>>(fc2_w,  wTfc2,  HID_, C_);
  concat_bias_kernel<<<C2_/256, 256, 0, stream>>>(actp_b, in_b, biasAI);
  zerofill_kernel<<<(B_*C_ + 255)/256, 256, 0, stream>>>(kmean, B_*C_);

  // x = x + cpe1(x); shortcut=x1; xn = LN(x)
  cpe_ln_kernel<float><<<BL_, 256, 0, stream>>>(x, cpe1_w, cpe1_b, norm1_g, norm1_b, x1, bufX);
  // fused: act_res = silu(xn @ actp_w + b) ; xi0 = xn @ in_w + b
  gemm_bf16<EP_ACTIN><<<dim3(BL_/128, C2_/128), 256, 0, stream>>>(
      bufX, wTai, biasAI, nullptr, nullptr, actres, xi0, BL_, C2_, C_);
  // xi = silu(dwc(xi0))
  dwconv_silu_kernel<<<BL_, 256, 0, stream>>>(xi0, dwc_w, dwc_b, xi);
  // qkb = elu(xi @ qk_w + b) + 1
  gemm_bf16<EP_ELU1><<<dim3(BL_/128, C2_/128), 256, 0, stream>>>(
      xi, wTqk, qk_b, nullptr, nullptr, qkb, nullptr, BL_, C2_, C_);
  // kmean, z, kv
  colmean_kernel<<<dim3(32, B_), 256, 0, stream>>>(qkb, kmean);
  z_kernel<<<BL_*H_/256, 256, 0, stream>>>(qkb, kmean, zbuf);
  kv_partial_kernel<<<dim3(128, 4), 256, 0, stream>>>(qkb, xi, cosS, sinS, kvpart);
  kv_reduce_kernel<<<128, 256, 0, stream>>>(kvpart, kvb);
  // attn (MFMA) + lepe + gating -> g (bf16, bufX overwrites xn)
  attn_kernel<<<dim3(16, B_, H_), 256, 0, stream>>>(
      qkb, xi, kvb, zbuf, cosS, sinS, lepe_w, lepe_b, actres, bufX);
  // x2 = x1 + g @ out_w + b   (bf16, into bufQ lower half; qkb dead)
  gemm_bf16<EP_RES_BF><<<dim3(BL_/128, C_/128), 256, 0, stream>>>(
      bufX, wTout, out_b, x1, nullptr, x2, nullptr, BL_, C_, C_);
  // x3 = x2 + cpe2(x2); xn2 = LN2(x3)
  cpe_ln_kernel<u16><<<BL_, 256, 0, stream>>>(x2, cpe2_w, cpe2_b, norm2_g, norm2_b, x3, bufX);
  // MLP in 4 row-chunks of 4096 (hidden chunk lives in bufW; xi dead)
  for (int m = 0; m < 4; ++m){
    size_t ro = (size_t)m * 4096;
    gemm_bf16<EP_GELU><<<dim3(32, HID_/128), 256, 0, stream>>>(
        bufX + ro * C_, wTfc1, fc1_b, nullptr, nullptr, hb, nullptr, 4096, HID_, C_);
    gemm_bf16<EP_RES_F32><<<dim3(32, C_/128), 256, 0, stream>>>(
        hb, wTfc2, fc2_b, x3 + ro * C_, out + ro * C_, nullptr, nullptr, 4096, C_, HID_);
  }
}

// Round 12
// 1174.714 us; speedup vs baseline: 1.3604x; 1.0724x over previous
//
#include <hip/hip_runtime.h>
#include <hip/hip_bf16.h>
#include <cstdint>

#define B_    8
#define L_    2048
#define C_    1024
#define H_    16
#define D_    64
#define BL_   16384
#define C2_   2048
#define HID_  4096
#define KMAX_ 512

typedef unsigned short u16;
typedef unsigned int   u32;
typedef __attribute__((ext_vector_type(8))) short short8;    // 8 bf16 (4 VGPRs)
typedef __attribute__((ext_vector_type(4))) float f32x4;
typedef __attribute__((ext_vector_type(16))) float f32x16;

__device__ __forceinline__ u16 f2bf(float f){
  u32 u = __float_as_uint(f);
  u += 0x7fffu + ((u >> 16) & 1u);      // RNE; inputs finite
  return (u16)(u >> 16);
}
__device__ __forceinline__ float bf2f(u16 v){
  return __uint_as_float(((u32)v) << 16);
}
// async global->LDS, 16B per lane; dest = wave-uniform base + lane*16
__device__ __forceinline__ void gld16(const void* g, void* l){
  __builtin_amdgcn_global_load_lds((const __attribute__((address_space(1))) u32*)g,
                                   (__attribute__((address_space(3))) u32*)l, 16, 0, 0);
}
// swizzle phases (chunk units, 0..7): A and B offset so consecutive reads
// (a0/a1 rows +32 -> XOR 4; B vs A -> XOR 5) hit distinct bank sets
__device__ __forceinline__ int swzA(int row){ return ((row ^ (row >> 3)) & 7) << 3; }
__device__ __forceinline__ int swzB(int row){ return ((((row ^ (row >> 3)) & 7) ^ 5)) << 3; }

// ---------------- zero fill ---------------------------------------------------
__global__ __launch_bounds__(256) void zerofill_kernel(float* __restrict__ p, int n){
  int i = blockIdx.x * 256 + threadIdx.x;
  if (i < n) p[i] = 0.f;
}

// ---------------- concat bias [actp_b | in_b] ---------------------------------
__global__ __launch_bounds__(256) void concat_bias_kernel(
    const float* __restrict__ b0, const float* __restrict__ b1, float* __restrict__ o){
  int i = blockIdx.x * 256 + threadIdx.x;
  if (i < C_) o[i] = b0[i];
  else if (i < C2_) o[i] = b1[i - C_];
}

// ---------------- rope table: theta = 10000^(-j/512) --------------------------
__global__ void rope_table_kernel(float* __restrict__ cosS, float* __restrict__ sinS){
  int t = threadIdx.x;
  if (t < KMAX_){
    float th = powf(10000.f, -(float)t / (float)KMAX_);
    cosS[t] = cosf(th);
    sinS[t] = sinf(th);
  }
}

// ---------------- f32 (R,Ccol) -> bf16 (Ccol,R) transpose ---------------------
__global__ __launch_bounds__(256) void transpose_bf16_kernel(
    const float* __restrict__ in, u16* __restrict__ out, int R, int Ccol)
{
  __shared__ float tile[32][33];
  int tx = threadIdx.x & 31, ty = threadIdx.x >> 5;   // 32 x 8
  int c = blockIdx.x * 32 + tx;
  #pragma unroll
  for (int i = 0; i < 4; ++i){
    int r = blockIdx.y * 32 + ty + i * 8;
    tile[ty + i * 8][tx] = in[(size_t)r * Ccol + c];
  }
  __syncthreads();
  int rr = blockIdx.y * 32 + tx;
  #pragma unroll
  for (int i = 0; i < 4; ++i){
    int cc = blockIdx.x * 32 + ty + i * 8;
    out[(size_t)cc * R + rr] = f2bf(tile[tx][ty + i * 8]);
  }
}

// ---------------- depthwise conv3 (+x residual) + LayerNorm -------------------
template<typename T>
__global__ __launch_bounds__(256) void cpe_ln_kernel(
    const T* __restrict__ xin, const float* __restrict__ cw, const float* __restrict__ cb,
    const float* __restrict__ g,   const float* __restrict__ beta,
    u16* __restrict__ xout, u16* __restrict__ xnout)
{
  int bl = blockIdx.x;
  int l  = bl & (L_ - 1);
  const T* xr = xin + (size_t)bl * C_;
  int t = threadIdx.x;
  float vals[4];
  float s = 0.f, ss = 0.f;
  #pragma unroll
  for (int i = 0; i < 4; ++i){
    int c = t + i * 256;
    float xm = (l > 0)      ? (float)xr[c - C_] : 0.f;
    float x0 = (float)xr[c];
    float xp = (l < L_ - 1) ? (float)xr[c + C_] : 0.f;
    float v = x0 + xm * cw[c*3] + x0 * cw[c*3+1] + xp * cw[c*3+2] + cb[c];
    vals[i] = v; s += v; ss += v * v;
  }
  int lane = t & 63, w = t >> 6;
  #pragma unroll
  for (int o = 32; o > 0; o >>= 1){ s += __shfl_down(s, o); ss += __shfl_down(ss, o); }
  __shared__ float red[8];
  __shared__ float sh[2];
  if (lane == 0){ red[w] = s; red[4 + w] = ss; }
  __syncthreads();
  if (t == 0){
    float S  = red[0] + red[1] + red[2] + red[3];
    float SS = red[4] + red[5] + red[6] + red[7];
    float mu = S * (1.f / C_);
    float var = SS * (1.f / C_) - mu * mu;
    sh[0] = mu; sh[1] = rsqrtf(var + 1e-5f);
  }
  __syncthreads();
  float mu = sh[0], inv = sh[1];
  #pragma unroll
  for (int i = 0; i < 4; ++i){
    int c = t + i * 256;
    float xn = (vals[i] - mu) * inv * g[c] + beta[c];
    xout[(size_t)bl * C_ + c]  = f2bf(vals[i]);
    xnout[(size_t)bl * C_ + c] = f2bf(xn);
  }
}
template<> __global__ __launch_bounds__(256) void cpe_ln_kernel<u16>(
    const u16* __restrict__ xin, const float* __restrict__ cw, const float* __restrict__ cb,
    const float* __restrict__ g,   const float* __restrict__ beta,
    u16* __restrict__ xout, u16* __restrict__ xnout)
{
  int bl = blockIdx.x;
  int l  = bl & (L_ - 1);
  const u16* xr = xin + (size_t)bl * C_;
  int t = threadIdx.x;
  float vals[4];
  float s = 0.f, ss = 0.f;
  #pragma unroll
  for (int i = 0; i < 4; ++i){
    int c = t + i * 256;
    float xm = (l > 0)      ? bf2f(xr[c - C_]) : 0.f;
    float x0 = bf2f(xr[c]);
    float xp = (l < L_ - 1) ? bf2f(xr[c + C_]) : 0.f;
    float v = x0 + xm * cw[c*3] + x0 * cw[c*3+1] + xp * cw[c*3+2] + cb[c];
    vals[i] = v; s += v; ss += v * v;
  }
  int lane = t & 63, w = t >> 6;
  #pragma unroll
  for (int o = 32; o > 0; o >>= 1){ s += __shfl_down(s, o); ss += __shfl_down(ss, o); }
  __shared__ float red[8];
  __shared__ float sh[2];
  if (lane == 0){ red[w] = s; red[4 + w] = ss; }
  __syncthreads();
  if (t == 0){
    float S  = red[0] + red[1] + red[2] + red[3];
    float SS = red[4] + red[5] + red[6] + red[7];
    float mu = S * (1.f / C_);
    float var = SS * (1.f / C_) - mu * mu;
    sh[0] = mu; sh[1] = rsqrtf(var + 1e-5f);
  }
  __syncthreads();
  float mu = sh[0], inv = sh[1];
  #pragma unroll
  for (int i = 0; i < 4; ++i){
    int c = t + i * 256;
    float xn = (vals[i] - mu) * inv * g[c] + beta[c];
    xout[(size_t)bl * C_ + c]  = f2bf(vals[i]);
    xnout[(size_t)bl * C_ + c] = f2bf(xn);
  }
}

// ---------------- depthwise conv3 + bias + silu (bf16 in -> bf16 out) --------
__global__ __launch_bounds__(256) void dwconv_silu_kernel(
    const u16* __restrict__ xin, const float* __restrict__ w, const float* __restrict__ bias,
    u16* __restrict__ xb)
{
  int bl = blockIdx.x;
  int l  = bl & (L_ - 1);
  const u16* xr = xin + (size_t)bl * C_;
  int t = threadIdx.x;
  #pragma unroll
  for (int i = 0; i < 4; ++i){
    int c = t + i * 256;
    float xm = (l > 0)      ? bf2f(xr[c - C_]) : 0.f;
    float x0 = bf2f(xr[c]);
    float xp = (l < L_ - 1) ? bf2f(xr[c + C_]) : 0.f;
    float v = xm * w[c*3] + x0 * w[c*3+1] + xp * w[c*3+2] + bias[c];
    v = v / (1.f + expf(-v));
    xb[(size_t)bl * C_ + c] = f2bf(v);
  }
}

// ---------------- column mean of k-half of qkb -> kmean[b][c] ----------------
__global__ __launch_bounds__(256) void colmean_kernel(
    const u16* __restrict__ qkb, float* __restrict__ kmean)
{
  int chunk = blockIdx.x, b = blockIdx.y;
  int l0 = chunk * 64;
  int t = threadIdx.x;
  #pragma unroll
  for (int i = 0; i < 4; ++i){
    int c = t + i * 256;
    float s = 0.f;
    for (int r = 0; r < 64; ++r)
      s += bf2f(qkb[((size_t)(b * L_ + l0 + r)) * C2_ + C_ + c]);
    atomicAdd(&kmean[b * C_ + c], s * (1.f / (float)L_));
  }
}

// ---------------- z[row*16+h] = 1/(q_h . kmean_h + 1e-6) ---------------------
__global__ __launch_bounds__(256) void z_kernel(
    const u16* __restrict__ qkb, const float* __restrict__ kmean,
    float* __restrict__ zg)
{
  int idx = blockIdx.x * 256 + threadIdx.x;   // row*16 + h
  int row = idx >> 4, h = idx & 15;
  int b = row >> 11;
  const u32* qp = (const u32*)(qkb + (size_t)row * C2_ + h * 64);
  const float2* kp = (const float2*)(kmean + b * C_ + h * 64);
  float dot = 0.f;
  #pragma unroll
  for (int i = 0; i < 32; ++i){
    u32 q2 = qp[i]; float2 k2 = kp[i];
    dot += bf2f((u16)(q2 & 0xffff)) * k2.x + bf2f((u16)(q2 >> 16)) * k2.y;
  }
  zg[idx] = 1.f / (dot + 1e-6f);
}

// ---------------- kv partial: per (b,h,chunk) accumulate k_rope ⊗ v ----------
// 32 rows staged per barrier pair (was 8): 32 barriers/block instead of 128
__global__ __launch_bounds__(256) void kv_partial_kernel(
    const u16* __restrict__ qkb, const u16* __restrict__ xi,
    const float* __restrict__ cosS, const float* __restrict__ sinS,
    float* __restrict__ part)
{
  int bh = blockIdx.x, cy = blockIdx.y;
  int b = bh >> 4, h = bh & 15;
  __shared__ float kl[32][64];
  __shared__ float vl[32][64];
  int t = threadIdx.x;
  int rsb = t >> 5, j = t & 31;         // staging role: row base, pair
  int d  = t >> 2, e0 = (t & 3) << 4;   // compute role
  float cj = cosS[h * 32 + j], sj = sinS[h * 32 + j];
  float acc[16];
  #pragma unroll
  for (int e = 0; e < 16; ++e) acc[e] = 0.f;
  int l0 = cy * 512;
  for (int it = 0; it < 16; ++it){
    #pragma unroll
    for (int rr = 0; rr < 4; ++rr){
      int r = rsb + rr * 8;
      int l = l0 + it * 32 + r;
      u32 kp = *(const u32*)(qkb + ((size_t)(b * L_ + l)) * C2_ + C_ + h * 64 + 2 * j);
      float k0 = bf2f((u16)(kp & 0xffff)), k1 = bf2f((u16)(kp >> 16));
      kl[r][2*j]   = k0 * cj - k1 * sj;
      kl[r][2*j+1] = k0 * sj + k1 * cj;
      u32 vp = *(const u32*)(xi + ((size_t)(b * L_ + l)) * C_ + h * 64 + 2 * j);
      vl[r][2*j]   = bf2f((u16)(vp & 0xffff));
      vl[r][2*j+1] = bf2f((u16)(vp >> 16));
    }
    __syncthreads();
    #pragma unroll
    for (int r = 0; r < 32; ++r){
      float kd = kl[r][d];
      #pragma unroll
      for (int e = 0; e < 16; ++e) acc[e] += kd * vl[r][e0 + e];
    }
    __syncthreads();
  }
  float* po = part + ((size_t)(bh * 4 + cy)) * 4096 + d * 64 + e0;
  #pragma unroll
  for (int e = 0; e < 16; ++e) po[e] = acc[e];
}

// reduce partials -> kvb bf16 TRANSPOSED [bh][e*64+d] (B-operand layout for MFMA)
__global__ __launch_bounds__(256) void kv_reduce_kernel(
    const float* __restrict__ part, u16* __restrict__ kvb)
{
  int bh = blockIdx.x;
  int t = threadIdx.x;
  #pragma unroll
  for (int i = 0; i < 16; ++i){
    int o = t + i * 256;
    int d = o >> 6, e = o & 63;
    float s = 0.f;
    #pragma unroll
    for (int cy = 0; cy < 4; ++cy)
      s += part[((size_t)(bh * 4 + cy)) * 4096 + o];
    kvb[(size_t)bh * 4096 + e * 64 + d] = f2bf(s * (1.f / (float)L_));
  }
}

// ---------------- fused attention epilogue (MFMA 16x16, verified) ------------
__global__ __launch_bounds__(256, 4) void attn_kernel(
    const u16* __restrict__ qkb, const u16* __restrict__ xi,
    const u16* __restrict__ kvb, const float* __restrict__ zg,
    const float* __restrict__ cosS, const float* __restrict__ sinS,
    const float* __restrict__ lw,  const float* __restrict__ lb,
    const u16* __restrict__ actres, u16* __restrict__ gout)
{
  int rc = blockIdx.x, b = blockIdx.y, h = blockIdx.z;
  __shared__ u16 qs[64 * 64];          // 8 KB, 128B rows, XOR-swizzled
  int t = threadIdx.x;
  int lane = t & 63, w = t >> 6;
  int bh = b * H_ + h;
  short8 bq[4][2];
  #pragma unroll
  for (int ni = 0; ni < 4; ++ni)
    #pragma unroll
    for (int kf = 0; kf < 2; ++kf)
      bq[ni][kf] = *(const short8*)(kvb + (size_t)bh * 4096 +
                     (ni * 16 + (lane & 15)) * 64 + kf * 32 + (lane >> 4) * 8);
  int js = t & 31;
  float cj = cosS[h * 32 + js], sj = sinS[h * 32 + js];
  float w0[4], w1[4], w2[4], bb[4];
  #pragma unroll
  for (int ni = 0; ni < 4; ++ni){
    int c = h * 64 + ni * 16 + (lane & 15);
    w0[ni] = lw[c*3]; w1[ni] = lw[c*3+1]; w2[ni] = lw[c*3+2]; bb[ni] = lb[c];
  }
  for (int ch = 0; ch < 2; ++ch){
    int n0 = rc * 128 + ch * 64;
    #pragma unroll
    for (int i = 0; i < 8; ++i){       // stage 64 roped rows as bf16
      int id = t + i * 256;
      int r = id >> 5;                 // pair index == js (low 5 bits)
      u32 q2 = *(const u32*)(qkb + ((size_t)(b * L_ + n0 + r)) * C2_ + h * 64 + 2 * js);
      float q0 = bf2f((u16)(q2 & 0xffff)), q1 = bf2f((u16)(q2 >> 16));
      u32 pk = (u32)f2bf(q0 * cj - q1 * sj) | ((u32)f2bf(q0 * sj + q1 * cj) << 16);
      *(u32*)((char*)qs + r * 128 + ((4 * js) ^ ((r & 7) << 4))) = pk;
    }
    __syncthreads();
    int arow = w * 16 + (lane & 15);
    short8 af0 = *(const short8*)((char*)qs + arow * 128 + ((     (lane >> 4) * 16) ^ ((arow & 7) << 4)));
    short8 af1 = *(const short8*)((char*)qs + arow * 128 + ((64 + (lane >> 4) * 16) ^ ((arow & 7) << 4)));
    f32x4 acc[4] = {};
    #pragma unroll
    for (int ni = 0; ni < 4; ++ni){
      acc[ni] = __builtin_amdgcn_mfma_f32_16x16x32_bf16(af0, bq[ni][0], acc[ni], 0, 0, 0);
      acc[ni] = __builtin_amdgcn_mfma_f32_16x16x32_bf16(af1, bq[ni][1], acc[ni], 0, 0, 0);
    }
    #pragma unroll
    for (int ni = 0; ni < 4; ++ni){
      int c = h * 64 + ni * 16 + (lane & 15);
      #pragma unroll
      for (int r = 0; r < 4; ++r){
        int n = n0 + w * 16 + (lane >> 4) * 4 + r;
        size_t row = (size_t)b * L_ + n;
        float attnv = acc[ni][r] * zg[(row << 4) + h];
        float vm = (n > 0)      ? bf2f(xi[(row - 1) * C_ + c]) : 0.f;
        float v0 = bf2f(xi[row * C_ + c]);
        float vp = (n < L_ - 1) ? bf2f(xi[(row + 1) * C_ + c]) : 0.f;
        float gval = (attnv + vm * w0[ni] + v0 * w1[ni] + vp * w2[ni] + bb[ni]) * bf2f(actres[row * C_ + c]);
        gout[row * C_ + c] = f2bf(gval);
      }
    }
    __syncthreads();
  }
}

// ---------------- bf16 MFMA GEMM, 128x128 tile, BK=64, 32x32x16 frags --------
// staging via global_load_lds w=16: linear LDS dest + inverse-swizzled global src
enum { EP_SILU = 0, EP_NONE = 1, EP_ELU1 = 2, EP_RES_BF = 3, EP_GELU = 4, EP_RES_F32 = 5, EP_ACTIN = 6 };

template<int EP>
__global__ __launch_bounds__(256) void gemm_bf16(
    const u16* __restrict__ A,    // M x K bf16 row-major
    const u16* __restrict__ Bt,   // N x K bf16 row-major (pre-transposed weight)
    const float* __restrict__ bias,
    const u16* __restrict__ res,  // bf16 residual (EP_RES_*)
    float* __restrict__ outF, u16* __restrict__ outB, u16* __restrict__ outB2,
    int M, int N, int K)
{
  __shared__ u16 As[128 * 64];
  __shared__ u16 Bs[128 * 64];
  const int t = threadIdx.x;
  const int m0 = blockIdx.x * 128;
  const int n0 = blockIdx.y * 128;
  const int lane = t & 63, w = t >> 6;
  const int wm = (w >> 1) * 64, wn = (w & 1) * 64;
  f32x16 acc00 = {}, acc01 = {}, acc10 = {}, acc11 = {};
  const int ktiles = K >> 6;
  for (int kt = 0; kt < ktiles; ++kt){
    const u16* Ab = A  + (size_t)m0 * K + kt * 64;
    const u16* Bb = Bt + (size_t)n0 * K + kt * 64;
    #pragma unroll
    for (int i = 0; i < 4; ++i){
      int idx = t + i * 256;
      int row = idx >> 3, k8 = idx & 7;
      int srcA = row * K + ((k8 * 8) ^ swzA(row));   // pre-swizzled sources
      int srcB = row * K + ((k8 * 8) ^ swzB(row));
      int wb = (i * 256 + (t & 192)) * 8;            // wave-uniform LDS base (u16 elems)
      gld16(Ab + srcA, &As[wb]);
      gld16(Bb + srcB, &Bs[wb]);
    }
    __syncthreads();   // compiler drains vmcnt before s_barrier
    // 32x32x16 fragments: A row=lane&31, k=(lane>>5)*8+j; B col=lane&31, same k
    const int rA0 = wm + (lane & 31), rA1 = rA0 + 32;
    const int rB0 = wn + (lane & 31), rB1 = rB0 + 32;
    const int sA0 = swzA(rA0), sA1 = swzA(rA1);
    const int sB0 = swzB(rB0), sB1 = swzB(rB1);
    #pragma unroll
    for (int ks = 0; ks < 4; ++ks){
      int kb = ks * 16 + ((lane >> 5) << 3);
      short8 a0 = *(const short8*)(&As[rA0 * 64 + (kb ^ sA0)]);
      short8 a1 = *(const short8*)(&As[rA1 * 64 + (kb ^ sA1)]);
      short8 b0 = *(const short8*)(&Bs[rB0 * 64 + (kb ^ sB0)]);
      short8 b1 = *(const short8*)(&Bs[rB1 * 64 + (kb ^ sB1)]);
      acc00 = __builtin_amdgcn_mfma_f32_32x32x16_bf16(a0, b0, acc00, 0, 0, 0);
      acc01 = __builtin_amdgcn_mfma_f32_32x32x16_bf16(a0, b1, acc01, 0, 0, 0);
      acc10 = __builtin_amdgcn_mfma_f32_32x32x16_bf16(a1, b0, acc10, 0, 0, 0);
      acc11 = __builtin_amdgcn_mfma_f32_32x32x16_bf16(a1, b1, acc11, 0, 0, 0);
    }
    __syncthreads();
  }
  // epilogue. 32x32 C/D: col=lane&31, row=(r&3)+8*(r>>2)+4*(lane>>5)
  const int rbase = (lane >> 5) << 2;
  #pragma unroll
  for (int mi = 0; mi < 2; ++mi){
    #pragma unroll
    for (int ni = 0; ni < 2; ++ni){
      const f32x16& a = (mi == 0) ? (ni == 0 ? acc00 : acc01) : (ni == 0 ? acc10 : acc11);
      int gn = n0 + wn + ni * 32 + (lane & 31);
      float bv = bias[gn];
      #pragma unroll
      for (int r = 0; r < 16; ++r){
        int gm = m0 + wm + mi * 32 + (r & 3) + ((r >> 2) << 3) + rbase;
        float v = a[r] + bv;
        size_t o = (size_t)gm * N + gn;
        if (EP == EP_SILU)      outB[o] = f2bf(v / (1.f + expf(-v)));
        else if (EP == EP_NONE) outB[o] = f2bf(v);
        else if (EP == EP_ELU1) outB[o] = f2bf((v > 0.f) ? (v + 1.f) : expf(v));
        else if (EP == EP_RES_BF) outB[o] = f2bf(v + bf2f(res[o]));
        else if (EP == EP_GELU){
          // tanh-form gelu: v*sigmoid(1.5957691v + 0.0713549v^3); |err|<~1e-3
          float u = v * (1.5957691f + 0.0713549f * v * v);
          outB[o] = f2bf(v / (1.f + expf(-u)));
        }
        else if (EP == EP_RES_F32) outF[o] = v + bf2f(res[o]);
        else if (EP == EP_ACTIN){
          int half = N >> 1;
          if (gn < half) outB[(size_t)gm * half + gn] = f2bf(v / (1.f + expf(-v)));
          else           outB2[(size_t)gm * half + gn - half] = f2bf(v);
        }
      }
    }
  }
}

// ------------------------------- launcher ------------------------------------
extern "C" void kernel_launch(void* const* d_in, const int* in_sizes, int n_in,
                              void* d_out, int out_size, void* d_ws, size_t ws_size,
                              hipStream_t stream)
{
  const float* x       = (const float*)d_in[0];
  const float* cpe1_w  = (const float*)d_in[1];
  const float* cpe1_b  = (const float*)d_in[2];
  const float* norm1_g = (const float*)d_in[3];
  const float* norm1_b = (const float*)d_in[4];
  const float* in_w    = (const float*)d_in[5];
  const float* in_b    = (const float*)d_in[6];
  const float* actp_w  = (const float*)d_in[7];
  const float* actp_b  = (const float*)d_in[8];
  const float* dwc_w   = (const float*)d_in[9];
  const float* dwc_b   = (const float*)d_in[10];
  const float* qk_w    = (const float*)d_in[11];
  const float* qk_b    = (const float*)d_in[12];
  const float* lepe_w  = (const float*)d_in[13];
  const float* lepe_b  = (const float*)d_in[14];
  const float* out_w   = (const float*)d_in[15];
  const float* out_b   = (const float*)d_in[16];
  const float* cpe2_w  = (const float*)d_in[17];
  const float* cpe2_b  = (const float*)d_in[18];
  const float* norm2_g = (const float*)d_in[19];
  const float* norm2_b = (const float*)d_in[20];
  const float* fc1_w   = (const float*)d_in[21];
  const float* fc1_b   = (const float*)d_in[22];
  const float* fc2_w   = (const float*)d_in[23];
  const float* fc2_b   = (const float*)d_in[24];
  float* out = (float*)d_out;

  char* ws = (char*)d_ws;
  size_t off = 0;
  auto alloc = [&](size_t bytes) -> char* {
    char* p = ws + off;
    off = (off + bytes + 255) & ~(size_t)255;
    return p;
  };
  float* cosS   = (float*)alloc(KMAX_ * 4);
  float* sinS   = (float*)alloc(KMAX_ * 4);
  u16* wTai     = (u16*)alloc((size_t)2 * C_ * C_ * 2);     // [actp^T | in^T] contiguous
  u16* wTqk     = (u16*)alloc((size_t)C2_ * C_ * 2);
  u16* wTout    = (u16*)alloc((size_t)C_ * C_ * 2);
  u16* wTfc1    = (u16*)alloc((size_t)HID_ * C_ * 2);
  u16* wTfc2    = (u16*)alloc((size_t)C_ * HID_ * 2);
  float* biasAI = (float*)alloc((size_t)C2_ * 4);
  float* kmean  = (float*)alloc((size_t)B_ * C_ * 4);
  u16*   kvb    = (u16*)alloc((size_t)128 * 4096 * 2);      // kv^T bf16 (B-frag layout)
  float* kvpart = (float*)alloc((size_t)512 * 4096 * 4);
  float* zbuf   = (float*)alloc((size_t)BL_ * H_ * 4);
  u16* x1       = (u16*)alloc((size_t)BL_ * C_ * 2);        // shortcut (bf16)
  u16* bufX     = (u16*)alloc((size_t)BL_ * C_ * 2);        // xn / g / xn2
  u16* bufY     = (u16*)alloc((size_t)BL_ * C_ * 2);        // act_res -> x3
  u16* bufW     = (u16*)alloc((size_t)BL_ * C_ * 2);        // xi
  u16* bufQ     = (u16*)alloc((size_t)BL_ * C2_ * 2);       // xi0 -> qkb -> x2 -> MLP hidden
  size_t needed = off;
  if (ws_size < needed) return;   // diagnostic: clean failure instead of OOB fault

  u16* wTactp = wTai;
  u16* wTin   = wTai + (size_t)C_ * C_;
  u16* xi0 = bufQ;        // 32MB (lower half)
  u16* qkb = bufQ;        // full 64MB
  u16* x2  = bufQ;        // 32MB (lower half), after qkb dead
  u16* hb  = bufQ;        // MLP hidden chunk 8192 x 4096 (full 64MB, after x2 dead)
  u16* xi  = bufW;
  u16* actres = bufY;
  u16* x3  = bufY;

  rope_table_kernel<<<1, 512, 0, stream>>>(cosS, sinS);
  transpose_bf16_kernel<<<dim3(C_/32,  C_/32 ), 256, 0, stream>>>(actp_w, wTactp, C_,  C_);
  transpose_bf16_kernel<<<dim3(C_/32,  C_/32 ), 256, 0, stream>>>(in_w,   wTin,   C_,  C_);
  transpose_bf16_kernel<<<dim3(C2_/32, C_/32 ), 256, 0, stream>>>(qk_w,   wTqk,   C_,  C2_);
  transpose_bf16_kernel<<<dim3(C_/32,  C_/32 ), 256, 0, stream>>>(out_w,  wTout,  C_,  C_);
  transpose_bf16_kernel<<<dim3(HID_/32,C_/32 ), 256, 0, stream>>>(fc1_w,  wTfc1,  C_,  HID_);
  transpose_bf16_kernel<<<dim3(C_/32,  HID_/32), 256, 0, stream>>>(fc2_w,  wTfc2,  HID_, C_);
  concat_bias_kernel<<<C2_/256, 256, 0, stream>>>(actp_b, in_b, biasAI);
  zerofill_kernel<<<(B_*C_ + 255)/256, 256, 0, stream>>>(kmean, B_*C_);

  // x = x + cpe1(x); shortcut=x1; xn = LN(x)
  cpe_ln_kernel<float><<<BL_, 256, 0, stream>>>(x, cpe1_w, cpe1_b, norm1_g, norm1_b, x1, bufX);
  // fused: act_res = silu(xn @ actp_w + b) ; xi0 = xn @ in_w + b
  gemm_bf16<EP_ACTIN><<<dim3(BL_/128, C2_/128), 256, 0, stream>>>(
      bufX, wTai, biasAI, nullptr, nullptr, actres, xi0, BL_, C2_, C_);
  // xi = silu(dwc(xi0))
  dwconv_silu_kernel<<<BL_, 256, 0, stream>>>(xi0, dwc_w, dwc_b, xi);
  // qkb = elu(xi @ qk_w + b) + 1
  gemm_bf16<EP_ELU1><<<dim3(BL_/128, C2_/128), 256, 0, stream>>>(
      xi, wTqk, qk_b, nullptr, nullptr, qkb, nullptr, BL_, C2_, C_);
  // kmean, z, kv
  colmean_kernel<<<dim3(32, B_), 256, 0, stream>>>(qkb, kmean);
  z_kernel<<<BL_*H_/256, 256, 0, stream>>>(qkb, kmean, zbuf);
  kv_partial_kernel<<<dim3(128, 4), 256, 0, stream>>>(qkb, xi, cosS, sinS, kvpart);
  kv_reduce_kernel<<<128, 256, 0, stream>>>(kvpart, kvb);
  // attn (MFMA) + lepe + gating -> g (bf16, bufX overwrites xn)
  attn_kernel<<<dim3(16, B_, H_), 256, 0, stream>>>(
      qkb, xi, kvb, zbuf, cosS, sinS, lepe_w, lepe_b, actres, bufX);
  // x2 = x1 + g @ out_w + b   (bf16, into bufQ lower half; qkb dead)
  gemm_bf16<EP_RES_BF><<<dim3(BL_/128, C_/128), 256, 0, stream>>>(
      bufX, wTout, out_b, x1, nullptr, x2, nullptr, BL_, C_, C_);
  // x3 = x2 + cpe2(x2); xn2 = LN2(x3)
  cpe_ln_kernel<u16><<<BL_, 256, 0, stream>>>(x2, cpe2_w, cpe2_b, norm2_g, norm2_b, x3, bufX);
  // MLP in 2 row-chunks of 8192 (hidden lives in bufQ; x2 dead after cpe_ln)
  for (int m = 0; m < 2; ++m){
    size_t ro = (size_t)m * 8192;
    gemm_bf16<EP_GELU><<<dim3(64, HID_/128), 256, 0, stream>>>(
        bufX + ro * C_, wTfc1, fc1_b, nullptr, nullptr, hb, nullptr, 8192, HID_, C_);
    gemm_bf16<EP_RES_F32><<<dim3(64, C_/128), 256, 0, stream>>>(
        hb, wTfc2, fc2_b, x3 + ro * C_, out + ro * C_, nullptr, nullptr, 8192, C_, HID_);
  }
}